// Round 3
// baseline (5800.542 us; speedup 1.0000x reference)
//
#include <hip/hip_runtime.h>
#include <hip/hip_bf16.h>
#include <cstdint>
#include <cstddef>

// ---------------------------------------------------------------------------
// SemanticTransformer forward, f32 compute; input/output dtype (bf16 vs f32)
// auto-detected at runtime via a probe kernel (flag in ws[0]).
// B=2, N=2048, C=256, NHEAD=4, DH=64, D2=384, G=16, Lp=512, layers=5
// ---------------------------------------------------------------------------

#define C_    256
#define DH_   64

__device__ __forceinline__ float b2f(unsigned short u) {
  union { unsigned int i; float f; } v; v.i = ((unsigned int)u) << 16; return v.f;
}
__device__ __forceinline__ unsigned short f2b(float f) {
  __hip_bfloat16 h = __float2bfloat16(f);
  union { __hip_bfloat16 h; unsigned short u; } v; v.h = h; return v.u;
}

// ---------------- dtype probe ----------------------------------------------
// Samples n ushorts of w as bf16. True bf16 weights (N(0,1/16)) are all tiny;
// f32 data read as ushorts contains mantissa junk -> huge/NaN values.
__global__ __launch_bounds__(256) void k_probe(int* __restrict__ flag,
                                               const unsigned short* __restrict__ w,
                                               int n) {
  __shared__ int ok[256];
  const int t = threadIdx.x;
  int good = 1;
  for (int i = t; i < n; i += 256) {
    float v = fabsf(b2f(w[i]));
    if (!(v < 1e3f)) good = 0;   // NaN compares false -> good=0
  }
  ok[t] = good;
  __syncthreads();
  for (int s = 128; s; s >>= 1) {
    if (t < s) ok[t] &= ok[t + s];
    __syncthreads();
  }
  if (t == 0) *flag = ok[0];   // 1 = bf16 data, 0 = f32 data
}

// ---------------- input load -> f32 ----------------------------------------
__global__ __launch_bounds__(256) void k_load(float* __restrict__ dst,
                                              const void* __restrict__ src,
                                              int n4, const int* __restrict__ flag) {
  int i = blockIdx.x * 256 + threadIdx.x;
  if (i >= n4) return;
  float4 f;
  if (*flag) {
    ushort4 u = ((const ushort4*)src)[i];
    f.x = b2f(u.x); f.y = b2f(u.y); f.z = b2f(u.z); f.w = b2f(u.w);
  } else {
    f = ((const float4*)src)[i];
  }
  ((float4*)dst)[i] = f;
}

// ---------------- output store ---------------------------------------------
__global__ __launch_bounds__(256) void k_store(void* __restrict__ out, size_t off,
                                               const float* __restrict__ src,
                                               int n4, const int* __restrict__ flag) {
  int i = blockIdx.x * 256 + threadIdx.x;
  if (i >= n4) return;
  float4 f = ((const float4*)src)[i];
  if (*flag) {
    ushort4 u;
    u.x = f2b(f.x); u.y = f2b(f.y); u.z = f2b(f.z); u.w = f2b(f.w);
    ((ushort4*)((unsigned short*)out + off))[i] = u;
  } else {
    ((float4*)((float*)out + off))[i] = f;
  }
}

__global__ __launch_bounds__(256) void k_add(float* __restrict__ dst,
                                             const float* __restrict__ src, int n4) {
  int i = blockIdx.x * 256 + threadIdx.x;
  if (i >= n4) return;
  float4 a = ((const float4*)dst)[i];
  float4 b = ((const float4*)src)[i];
  a.x += b.x; a.y += b.y; a.z += b.z; a.w += b.w;
  ((float4*)dst)[i] = a;
}

// ---------------- GEMM: Y(RxN) = X(RxK) @ W[rowOff:rowOff+K](KxN) ----------
// W dtype picked by *dflag (1=bf16, 0=f32). flags: bit0=relu, bit1=accum.
__global__ __launch_bounds__(256) void k_gemm(float* __restrict__ Y,
                                              const float* __restrict__ X,
                                              const void* __restrict__ W,
                                              int K, int Nw, int flags, int rowOff,
                                              const int* __restrict__ dflag) {
  __shared__ float As[16][64];    // [k][m]
  __shared__ float Bs[16][68];    // [k][n], 68*4=272 B keeps 16B row align
  const int isbf = *dflag;
  const unsigned short* Wb = (const unsigned short*)W;
  const float* Wf = (const float*)W;
  const int tid = threadIdx.x;
  const int tx = tid & 15, ty = tid >> 4;
  const int m0 = blockIdx.y * 64, n0 = blockIdx.x * 64;
  const int ar = tid >> 2, ak = (tid & 3) << 2;   // A: row, k-base
  const int bk = tid >> 4, bc = (tid & 15) << 2;  // B: k,   col-base

  float acc00=0,acc01=0,acc02=0,acc03=0;
  float acc10=0,acc11=0,acc12=0,acc13=0;
  float acc20=0,acc21=0,acc22=0,acc23=0;
  float acc30=0,acc31=0,acc32=0,acc33=0;

  for (int k0 = 0; k0 < K; k0 += 16) {
    __syncthreads();
    float4 av = *(const float4*)(X + (size_t)(m0 + ar) * K + k0 + ak);
    As[ak+0][ar] = av.x; As[ak+1][ar] = av.y; As[ak+2][ar] = av.z; As[ak+3][ar] = av.w;
    const size_t widx = (size_t)(rowOff + k0 + bk) * Nw + n0 + bc;
    if (isbf) {
      ushort4 wv = *(const ushort4*)(Wb + widx);
      Bs[bk][bc+0] = b2f(wv.x); Bs[bk][bc+1] = b2f(wv.y);
      Bs[bk][bc+2] = b2f(wv.z); Bs[bk][bc+3] = b2f(wv.w);
    } else {
      float4 wv = *(const float4*)(Wf + widx);
      Bs[bk][bc+0] = wv.x; Bs[bk][bc+1] = wv.y;
      Bs[bk][bc+2] = wv.z; Bs[bk][bc+3] = wv.w;
    }
    __syncthreads();
#pragma unroll
    for (int kk = 0; kk < 16; ++kk) {
      float4 a = *(const float4*)&As[kk][ty << 2];
      float4 b = *(const float4*)&Bs[kk][tx << 2];
      acc00 = fmaf(a.x, b.x, acc00); acc01 = fmaf(a.x, b.y, acc01);
      acc02 = fmaf(a.x, b.z, acc02); acc03 = fmaf(a.x, b.w, acc03);
      acc10 = fmaf(a.y, b.x, acc10); acc11 = fmaf(a.y, b.y, acc11);
      acc12 = fmaf(a.y, b.z, acc12); acc13 = fmaf(a.y, b.w, acc13);
      acc20 = fmaf(a.z, b.x, acc20); acc21 = fmaf(a.z, b.y, acc21);
      acc22 = fmaf(a.z, b.z, acc22); acc23 = fmaf(a.z, b.w, acc23);
      acc30 = fmaf(a.w, b.x, acc30); acc31 = fmaf(a.w, b.y, acc31);
      acc32 = fmaf(a.w, b.z, acc32); acc33 = fmaf(a.w, b.w, acc33);
    }
  }

  float rows[4][4] = {{acc00,acc01,acc02,acc03},{acc10,acc11,acc12,acc13},
                      {acc20,acc21,acc22,acc23},{acc30,acc31,acc32,acc33}};
#pragma unroll
  for (int i = 0; i < 4; ++i) {
    float* yp = Y + (size_t)(m0 + (ty<<2) + i) * Nw + n0 + (tx<<2);
    float4 v; v.x = rows[i][0]; v.y = rows[i][1]; v.z = rows[i][2]; v.w = rows[i][3];
    if (flags & 2) {
      float4 old = *(const float4*)yp;
      v.x += old.x; v.y += old.y; v.z += old.z; v.w += old.w;
    }
    if (flags & 1) {
      v.x = fmaxf(v.x, 0.f); v.y = fmaxf(v.y, 0.f);
      v.z = fmaxf(v.z, 0.f); v.w = fmaxf(v.w, 0.f);
    }
    *(float4*)yp = v;
  }
}

// ---------------- flash attention, split-S partials -------------------------
__global__ __launch_bounds__(64) void k_attn_partial(float* __restrict__ pO,
                                                     float* __restrict__ pML,
                                                     const float* __restrict__ Q,
                                                     const float* __restrict__ Kb,
                                                     const float* __restrict__ Vb,
                                                     int L, int S, int split) {
  const int q  = blockIdx.x * 64 + threadIdx.x;
  const int nh = blockIdx.y;
  const int NHt = gridDim.y;
  const int n = nh >> 2, h = nh & 3;
  const int sp = blockIdx.z;
  const int chunk = S / split;
  const int s0 = sp * chunk;

  const float* qp = Q + ((size_t)n * L + q) * C_ + h * DH_;
  float4 qr[16];
#pragma unroll
  for (int i = 0; i < 16; ++i) qr[i] = ((const float4*)qp)[i];
  float4 o[16];
#pragma unroll
  for (int i = 0; i < 16; ++i) { o[i].x = 0.f; o[i].y = 0.f; o[i].z = 0.f; o[i].w = 0.f; }
  float m = -1e30f, l = 0.f;

  const float* kbase = Kb + ((size_t)n * S + s0) * C_ + h * DH_;
  const float* vbase = Vb + ((size_t)n * S + s0) * C_ + h * DH_;

  for (int s = 0; s < chunk; ++s) {
    const float4* kp = (const float4*)(kbase + (size_t)s * C_);
    float a0 = 0.f, a1 = 0.f, a2 = 0.f, a3 = 0.f;
#pragma unroll
    for (int i = 0; i < 16; ++i) {
      float4 kv = kp[i];
      a0 = fmaf(qr[i].x, kv.x, a0);
      a1 = fmaf(qr[i].y, kv.y, a1);
      a2 = fmaf(qr[i].z, kv.z, a2);
      a3 = fmaf(qr[i].w, kv.w, a3);
    }
    float sc = ((a0 + a1) + (a2 + a3)) * 0.125f;  // 1/sqrt(64)
    float mn = fmaxf(m, sc);
    float alpha = __expf(m - mn);
    float e = __expf(sc - mn);
    l = fmaf(l, alpha, e);
    const float4* vp = (const float4*)(vbase + (size_t)s * C_);
#pragma unroll
    for (int i = 0; i < 16; ++i) {
      float4 vv = vp[i];
      o[i].x = fmaf(o[i].x, alpha, e * vv.x);
      o[i].y = fmaf(o[i].y, alpha, e * vv.y);
      o[i].z = fmaf(o[i].z, alpha, e * vv.z);
      o[i].w = fmaf(o[i].w, alpha, e * vv.w);
    }
    m = mn;
  }

  float* po = pO + (((size_t)sp * NHt + nh) * L + q) * 64;
#pragma unroll
  for (int i = 0; i < 16; ++i) ((float4*)po)[i] = o[i];
  float* pml = pML + (((size_t)sp * NHt + nh) * L + q) * 2;
  pml[0] = m; pml[1] = l;
}

__global__ __launch_bounds__(256) void k_attn_combine(float* __restrict__ O,
                                                      const float* __restrict__ pO,
                                                      const float* __restrict__ pML,
                                                      int L, int split) {
  const int tid = threadIdx.x;
  const int q = blockIdx.x * 64 + (tid >> 2);
  const int part = tid & 3;
  const int nh = blockIdx.y, NHt = gridDim.y;
  const int n = nh >> 2, h = nh & 3;

  float M = -1e30f;
  for (int sp = 0; sp < split; ++sp)
    M = fmaxf(M, pML[(((size_t)sp * NHt + nh) * L + q) * 2 + 0]);

  float4 acc[4];
#pragma unroll
  for (int i = 0; i < 4; ++i) { acc[i].x=0.f; acc[i].y=0.f; acc[i].z=0.f; acc[i].w=0.f; }
  float lsum = 0.f;
  for (int sp = 0; sp < split; ++sp) {
    const float* pml = pML + (((size_t)sp * NHt + nh) * L + q) * 2;
    float e = __expf(pml[0] - M);
    lsum = fmaf(pml[1], e, lsum);
    const float4* po = (const float4*)(pO + (((size_t)sp * NHt + nh) * L + q) * 64 + part * 16);
#pragma unroll
    for (int i = 0; i < 4; ++i) {
      float4 v = po[i];
      acc[i].x = fmaf(v.x, e, acc[i].x);
      acc[i].y = fmaf(v.y, e, acc[i].y);
      acc[i].z = fmaf(v.z, e, acc[i].z);
      acc[i].w = fmaf(v.w, e, acc[i].w);
    }
  }
  float inv = 1.0f / lsum;
  float* op = O + ((size_t)n * L + q) * C_ + h * DH_ + part * 16;
#pragma unroll
  for (int i = 0; i < 4; ++i) {
    float4 v; v.x = acc[i].x*inv; v.y = acc[i].y*inv; v.z = acc[i].z*inv; v.w = acc[i].w*inv;
    ((float4*)op)[i] = v;
  }
}

// ---------------- LayerNorm over 256 (no affine) ----------------------------
__device__ __forceinline__ void row_stats(float4 v, float& mean, float& inv) {
  float s  = v.x + v.y + v.z + v.w;
  float s2 = fmaf(v.x, v.x, fmaf(v.y, v.y, fmaf(v.z, v.z, v.w * v.w)));
#pragma unroll
  for (int off = 32; off >= 1; off >>= 1) {
    s  += __shfl_xor(s,  off, 64);
    s2 += __shfl_xor(s2, off, 64);
  }
  mean = s * (1.f / 256.f);
  float var = s2 * (1.f / 256.f) - mean * mean;
  inv = rsqrtf(var + 1e-5f);
}

__global__ __launch_bounds__(64) void k_ln(float* __restrict__ dst,
                                           const float* __restrict__ src) {
  const size_t row = blockIdx.x;
  const int t = threadIdx.x;
  float4 v = ((const float4*)(src + row * 256))[t];
  float mean, inv; row_stats(v, mean, inv);
  v.x = (v.x - mean) * inv; v.y = (v.y - mean) * inv;
  v.z = (v.z - mean) * inv; v.w = (v.w - mean) * inv;
  ((float4*)(dst + row * 256))[t] = v;
}

__global__ __launch_bounds__(64) void k_ln_add_f32(float* __restrict__ dst,
                                                   const float* __restrict__ x,
                                                   const float* __restrict__ t3) {
  const size_t row = blockIdx.x;
  const int t = threadIdx.x;
  float4 v = ((const float4*)(t3 + row * 256))[t];
  float mean, inv; row_stats(v, mean, inv);
  float4 xv = ((const float4*)(x + row * 256))[t];
  float4 r;
  r.x = xv.x + (v.x - mean) * inv; r.y = xv.y + (v.y - mean) * inv;
  r.z = xv.z + (v.z - mean) * inv; r.w = xv.w + (v.w - mean) * inv;
  ((float4*)(dst + row * 256))[t] = r;
}

__global__ __launch_bounds__(64) void k_ln_add_out(void* __restrict__ out, size_t off,
                                                   const float* __restrict__ x,
                                                   const float* __restrict__ t3,
                                                   const int* __restrict__ flag) {
  const size_t row = blockIdx.x;
  const int t = threadIdx.x;
  float4 v = ((const float4*)(t3 + row * 256))[t];
  float mean, inv; row_stats(v, mean, inv);
  float4 xv = ((const float4*)(x + row * 256))[t];
  float4 r;
  r.x = xv.x + (v.x - mean) * inv; r.y = xv.y + (v.y - mean) * inv;
  r.z = xv.z + (v.z - mean) * inv; r.w = xv.w + (v.w - mean) * inv;
  if (*flag) {
    ushort4 u;
    u.x = f2b(r.x); u.y = f2b(r.y); u.z = f2b(r.z); u.w = f2b(r.w);
    ((ushort4*)((unsigned short*)out + off + row * 256))[t] = u;
  } else {
    ((float4*)((float*)out + off + row * 256))[t] = r;
  }
}

// ---------------- semantic gather (index 2048 -> zeros) ---------------------
__global__ __launch_bounds__(64) void k_gather(float* __restrict__ dst,
                                               const float* __restrict__ srcF,
                                               const int* __restrict__ idx) {
  const int row = blockIdx.x;         // 0..8191 = g*512 + l
  const int g = row >> 9;
  const int b = g >> 3;               // mask_num = 8
  const int id = idx[row];
  float4 v; v.x = 0.f; v.y = 0.f; v.z = 0.f; v.w = 0.f;
  if ((unsigned)id < 2048u)
    v = ((const float4*)(srcF + ((size_t)b * 2048 + id) * 256))[threadIdx.x];
  ((float4*)(dst + (size_t)row * 256))[threadIdx.x] = v;
}

// ---------------------------------------------------------------------------
extern "C" void kernel_launch(void* const* d_in, const int* in_sizes, int n_in,
                              void* d_out, int out_size, void* d_ws, size_t ws_size,
                              hipStream_t stream) {
  const void* src_feat = d_in[0];
  const void* tgt_feat = d_in[1];
  const int* s_sub = (const int*)d_in[6];
  const int* t_sub = (const int*)d_in[7];
  const void* src2d = d_in[11];
  const void* tgt2d = d_in[12];
  const void* dinoW = d_in[14];
  const void* qW = d_in[15];
  const void* kW = d_in[16];
  const void* vW = d_in[17];
  const void* mW = d_in[18];
  const void* w1 = d_in[19];
  const void* w2 = d_in[20];

  int* dflag = (int*)d_ws;
  float* ws = (float*)d_ws + 16;
  const size_t SZ_FEAT = 1048576;         // 2*2048*256
  float* sF   = ws;
  float* tF   = sF   + SZ_FEAT;
  float* s2   = tF   + SZ_FEAT;
  float* t2   = s2   + SZ_FEAT;
  float* sSub = t2   + SZ_FEAT;           // 16*512*256 = 2097152
  float* tSub = sSub + 2097152;
  float* qwb  = tSub + 2097152;           // scratch, 8192x256 each
  float* kwb  = qwb  + 2097152;
  float* vwb  = kwb  + 2097152;
  float* ob   = vwb  + 2097152;
  float* t2b  = ob   + 2097152;           // 8192x512
  float* pO   = t2b  + 4194304;           // 8*8*2048*64 == 4*64*512*64
  float* pML  = pO   + 8388608;           // 262144
  // total ~113 MB

  // probe dtype once (qW values ~N(0,1/16))
  k_probe<<<1, 256, 0, stream>>>(dflag, (const unsigned short*)qW, 4096);

  auto gemm = [&](float* Y, const float* X, const void* Wp, int rowOff,
                  int R, int K, int Nw, int flags) {
    dim3 g(Nw / 64, R / 64);
    k_gemm<<<g, 256, 0, stream>>>(Y, X, Wp, K, Nw, flags, rowOff, dflag);
  };

  auto attn = [&](int layer, const float* X, const float* Src,
                  int bs, int L, int S, int split,
                  float* dstF, size_t outOff) {
    const int R = bs * L, Rs = bs * S;
    gemm(qwb, X,   qW, layer * 256, R,  256, 256, 0);
    gemm(kwb, Src, kW, layer * 256, Rs, 256, 256, 0);
    gemm(vwb, Src, vW, layer * 256, Rs, 256, 256, 0);
    k_attn_partial<<<dim3(L / 64, bs * 4, split), 64, 0, stream>>>(
        pO, pML, qwb, kwb, vwb, L, S, split);
    k_attn_combine<<<dim3(L / 64, bs * 4), 256, 0, stream>>>(ob, pO, pML, L, split);
    gemm(qwb, ob, mW, layer * 256, R, 256, 256, 0);   // t1 = o @ mW
    k_ln<<<R, 64, 0, stream>>>(kwb, qwb);             // msg = LN(t1)
    gemm(t2b, X,   w1, layer * 512,       R, 256, 512, 0);      // x @ w1_top
    gemm(t2b, kwb, w1, layer * 512 + 256, R, 256, 512, 1 | 2);  // += msg @ w1_bot, relu
    gemm(ob, t2b, w2, layer * 512, R, 512, 256, 0);   // t3
    if (dstF) k_ln_add_f32<<<R, 64, 0, stream>>>(dstF, X, ob);
    else      k_ln_add_out<<<R, 64, 0, stream>>>(d_out, outOff, X, ob, dflag);
  };

  // ---- init: load feats to f32; dino projections ----
  k_load<<<1024, 256, 0, stream>>>(sF, src_feat, 262144, dflag);
  k_load<<<1024, 256, 0, stream>>>(tF, tgt_feat, 262144, dflag);
  k_load<<<1536, 256, 0, stream>>>(qwb, src2d, 393216, dflag);
  gemm(s2, qwb, dinoW, 0, 4096, 384, 256, 0);
  k_load<<<1536, 256, 0, stream>>>(qwb, tgt2d, 393216, dflag);
  gemm(t2, qwb, dinoW, 0, 4096, 384, 256, 0);

  const int MS = 8, SS = 4;  // split-S for main / semantic attention

  // layer 0: self
  k_add<<<1024, 256, 0, stream>>>(sF, s2, 262144);
  k_add<<<1024, 256, 0, stream>>>(tF, t2, 262144);
  attn(0, sF, sF, 2, 2048, 2048, MS, sF, 0);
  attn(0, tF, tF, 2, 2048, 2048, MS, tF, 0);
  // layer 1: cross (tgt uses updated src)
  attn(1, sF, tF, 2, 2048, 2048, MS, sF, 0);
  attn(1, tF, sF, 2, 2048, 2048, MS, tF, 0);
  // layer 2: self (re-add dino projections)
  k_add<<<1024, 256, 0, stream>>>(sF, s2, 262144);
  k_add<<<1024, 256, 0, stream>>>(tF, t2, 262144);
  attn(2, sF, sF, 2, 2048, 2048, MS, sF, 0);
  attn(2, tF, tF, 2, 2048, 2048, MS, tF, 0);
  // layer 3: cross
  attn(3, sF, tF, 2, 2048, 2048, MS, sF, 0);
  attn(3, tF, sF, 2, 2048, 2048, MS, tF, 0);
  // semantic gather (pad index 2048 -> zeros)
  k_gather<<<8192, 64, 0, stream>>>(sSub, sF, s_sub);
  k_gather<<<8192, 64, 0, stream>>>(tSub, tF, t_sub);
  // layer 4: semantic subspace cross — both use ORIGINAL ssub/tsub
  attn(4, sSub, tSub, 16, 512, 512, SS, nullptr, 2097152);
  attn(4, tSub, sSub, 16, 512, 512, SS, nullptr, 4194304);

  // main outputs
  k_store<<<1024, 256, 0, stream>>>(d_out, 0,       sF, 262144, dflag);
  k_store<<<1024, 256, 0, stream>>>(d_out, 1048576, tF, 262144, dflag);
}

// Round 4
// 1865.383 us; speedup vs baseline: 3.1096x; 3.1096x over previous
//
#include <hip/hip_runtime.h>
#include <hip/hip_bf16.h>
#include <cstdint>
#include <cstddef>

// ---------------------------------------------------------------------------
// SemanticTransformer forward. bf16 MFMA compute, f32 residual stream.
// Input/output dtype (bf16 vs f32) auto-detected via probe (flag in ws).
// B=2, N=2048, C=256, NHEAD=4, DH=64, D2=384, G=16, Lp=512, layers=5
// ---------------------------------------------------------------------------

typedef __attribute__((ext_vector_type(8))) short bf16x8;   // 8 bf16, 4 VGPRs
typedef __attribute__((ext_vector_type(4))) float f32x4;

__device__ __forceinline__ float b2f(unsigned short u) {
  union { unsigned int i; float f; } v; v.i = ((unsigned int)u) << 16; return v.f;
}
__device__ __forceinline__ unsigned short f2b(float f) {
  __hip_bfloat16 h = __float2bfloat16(f);
  union { __hip_bfloat16 h; unsigned short u; } v; v.h = h; return v.u;
}

// ---------------- dtype probe ----------------------------------------------
__global__ __launch_bounds__(256) void k_probe(int* __restrict__ flag,
                                               const unsigned short* __restrict__ w,
                                               int n) {
  __shared__ int ok[256];
  const int t = threadIdx.x;
  int good = 1;
  for (int i = t; i < n; i += 256) {
    float v = fabsf(b2f(w[i]));
    if (!(v < 1e3f)) good = 0;
  }
  ok[t] = good;
  __syncthreads();
  for (int s = 128; s; s >>= 1) {
    if (t < s) ok[t] &= ok[t + s];
    __syncthreads();
  }
  if (t == 0) *flag = ok[0];   // 1 = bf16 data, 0 = f32 data
}

// ---------------- input loads ----------------------------------------------
__global__ __launch_bounds__(256) void k_load2(float* __restrict__ dF,
                                               unsigned short* __restrict__ dB,
                                               const void* __restrict__ src,
                                               int n4, const int* __restrict__ flag) {
  int i = blockIdx.x * 256 + threadIdx.x;
  if (i >= n4) return;
  float4 f;
  if (*flag) {
    ushort4 u = ((const ushort4*)src)[i];
    f.x = b2f(u.x); f.y = b2f(u.y); f.z = b2f(u.z); f.w = b2f(u.w);
  } else {
    f = ((const float4*)src)[i];
  }
  ((float4*)dF)[i] = f;
  ushort4 o; o.x = f2b(f.x); o.y = f2b(f.y); o.z = f2b(f.z); o.w = f2b(f.w);
  ((ushort4*)dB)[i] = o;
}

__global__ __launch_bounds__(256) void k_loadb(unsigned short* __restrict__ dB,
                                               const void* __restrict__ src,
                                               int n4, const int* __restrict__ flag) {
  int i = blockIdx.x * 256 + threadIdx.x;
  if (i >= n4) return;
  float4 f;
  if (*flag) {
    ((ushort4*)dB)[i] = ((const ushort4*)src)[i];
    return;
  }
  f = ((const float4*)src)[i];
  ushort4 o; o.x = f2b(f.x); o.y = f2b(f.y); o.z = f2b(f.z); o.w = f2b(f.w);
  ((ushort4*)dB)[i] = o;
}

__global__ __launch_bounds__(256) void k_store(void* __restrict__ out, size_t off,
                                               const float* __restrict__ src,
                                               int n4, const int* __restrict__ flag) {
  int i = blockIdx.x * 256 + threadIdx.x;
  if (i >= n4) return;
  float4 f = ((const float4*)src)[i];
  if (*flag) {
    ushort4 u; u.x = f2b(f.x); u.y = f2b(f.y); u.z = f2b(f.z); u.w = f2b(f.w);
    ((ushort4*)((unsigned short*)out + off))[i] = u;
  } else {
    ((float4*)((float*)out + off))[i] = f;
  }
}

// dino residual: xF += addB; xB = bf16(xF)
__global__ __launch_bounds__(256) void k_add_dino(float* __restrict__ xF,
                                                  unsigned short* __restrict__ xB,
                                                  const unsigned short* __restrict__ addB,
                                                  int n4) {
  int i = blockIdx.x * 256 + threadIdx.x;
  if (i >= n4) return;
  float4 a = ((const float4*)xF)[i];
  ushort4 u = ((const ushort4*)addB)[i];
  a.x += b2f(u.x); a.y += b2f(u.y); a.z += b2f(u.z); a.w += b2f(u.w);
  ((float4*)xF)[i] = a;
  ushort4 o; o.x = f2b(a.x); o.y = f2b(a.y); o.z = f2b(a.z); o.w = f2b(a.w);
  ((ushort4*)xB)[i] = o;
}

// ---------------- weight transpose+cast: Wt[z][n][k] = W[z][k][n] ----------
__global__ __launch_bounds__(256) void k_wt(unsigned short* __restrict__ Wt,
                                            const void* __restrict__ W,
                                            int K, int N, const int* __restrict__ flag) {
  __shared__ float tile[32][33];
  const int isbf = *flag;
  const int z = blockIdx.z;
  const unsigned short* Wb = (const unsigned short*)W + (size_t)z * K * N;
  const float* Wf = (const float*)W + (size_t)z * K * N;
  unsigned short* Wo = Wt + (size_t)z * N * K;
  const int nx = blockIdx.x * 32, ky = blockIdx.y * 32;
  const int tx = threadIdx.x & 31, ty = threadIdx.x >> 5;  // ty 0..7
#pragma unroll
  for (int i = 0; i < 4; ++i) {
    int k = ky + ty + i * 8;
    float v = isbf ? b2f(Wb[(size_t)k * N + nx + tx]) : Wf[(size_t)k * N + nx + tx];
    tile[ty + i * 8][tx] = v;
  }
  __syncthreads();
#pragma unroll
  for (int i = 0; i < 4; ++i) {
    int nn = ty + i * 8;
    Wo[(size_t)(nx + nn) * K + ky + tx] = f2b(tile[tx][nn]);
  }
}

// ---------------- MFMA GEMM: Y(MxN) = A(MxKtot) @ W(KtotxN) ----------------
// A is bf16 row-major (concat: k<K1 from A1, else A2). Wt is W^T bf16 (N x Ktot).
// Tile 64x64, 4 waves x 16 rows. Output bf16, optional relu.
__global__ __launch_bounds__(256) void k_gmm(unsigned short* __restrict__ Y,
                                             const unsigned short* __restrict__ A1, int lda1,
                                             const unsigned short* __restrict__ A2, int lda2,
                                             int K1, const unsigned short* __restrict__ Wt,
                                             int Ktot, int N, int relu) {
  const int tid = threadIdx.x;
  const int wq = tid >> 6, lane = tid & 63;
  const int l16 = lane & 15, quad = lane >> 4;
  const int n0 = blockIdx.x * 64, m0 = blockIdx.y * 64;
  const int row = m0 + wq * 16 + l16;

  f32x4 acc[4];
#pragma unroll
  for (int i = 0; i < 4; ++i) acc[i] = (f32x4){0.f, 0.f, 0.f, 0.f};

  for (int k0 = 0; k0 < Ktot; k0 += 32) {
    const unsigned short* ap = (k0 < K1)
        ? (A1 + (size_t)row * lda1 + k0)
        : (A2 + (size_t)row * lda2 + (k0 - K1));
    bf16x8 a = *(const bf16x8*)(ap + quad * 8);
#pragma unroll
    for (int nb = 0; nb < 4; ++nb) {
      bf16x8 b = *(const bf16x8*)(Wt + (size_t)(n0 + nb * 16 + l16) * Ktot + k0 + quad * 8);
      acc[nb] = __builtin_amdgcn_mfma_f32_16x16x32_bf16(a, b, acc[nb], 0, 0, 0);
    }
  }

#pragma unroll
  for (int r = 0; r < 4; ++r) {
    const size_t orow = (size_t)(m0 + wq * 16 + quad * 4 + r) * N;
#pragma unroll
    for (int nb = 0; nb < 4; ++nb) {
      float v = acc[nb][r];
      if (relu) v = fmaxf(v, 0.f);
      Y[orow + n0 + nb * 16 + l16] = f2b(v);
    }
  }
}

// ---------------- MFMA flash attention -------------------------------------
// Q,K,V: (n, L|S, 256) bf16, head h at col h*64. One workgroup = (n,h) x 64-query
// tile; 4 waves x 16 queries. Iterate S in 64-key tiles.
__global__ __launch_bounds__(256) void k_attn(unsigned short* __restrict__ O,
                                              const unsigned short* __restrict__ Q,
                                              const unsigned short* __restrict__ K,
                                              const unsigned short* __restrict__ V,
                                              int L, int S) {
  __shared__ __align__(16) unsigned short Vt[64][72];      // V^T: [dh][key]
  __shared__ __align__(16) unsigned short Pl[4][16][72];   // per-wave P: [q][key]
  const int tid = threadIdx.x;
  const int wq = tid >> 6, lane = tid & 63;
  const int l16 = lane & 15, quad = lane >> 4;
  const int q0 = blockIdx.x * 64;
  const int nh = blockIdx.y;
  const int n = nh >> 2, h = nh & 3;

  // Q A-fragments for this wave's 16 rows (held for the whole kernel)
  const unsigned short* qp = Q + ((size_t)(n * L + q0 + wq * 16 + l16)) * 256 + h * 64;
  bf16x8 qa0 = *(const bf16x8*)(qp + quad * 8);
  bf16x8 qa1 = *(const bf16x8*)(qp + 32 + quad * 8);

  f32x4 acc[4];
#pragma unroll
  for (int i = 0; i < 4; ++i) acc[i] = (f32x4){0.f, 0.f, 0.f, 0.f};
  float m_[4], l_[4];
#pragma unroll
  for (int r = 0; r < 4; ++r) { m_[r] = -1e30f; l_[r] = 0.f; }

  const int sdh0 = wq * 16;       // staging: wave wq handles dh rows [wq*16, +16)
  const int skey = lane;          //          lane = key

  for (int s0 = 0; s0 < S; s0 += 64) {
    __syncthreads();  // protect Vt from previous tile's readers
    // stage V^T tile (coalesced global read, conflict-free LDS scatter)
    {
      const unsigned short* vp = V + ((size_t)n * S + s0 + skey) * 256 + h * 64 + sdh0;
      uint4 v0 = *(const uint4*)vp;
      uint4 v1 = *(const uint4*)(vp + 8);
      const unsigned short* p0 = (const unsigned short*)&v0;
      const unsigned short* p1 = (const unsigned short*)&v1;
#pragma unroll
      for (int i = 0; i < 8; ++i) Vt[sdh0 + i][skey] = p0[i];
#pragma unroll
      for (int i = 0; i < 8; ++i) Vt[sdh0 + 8 + i][skey] = p1[i];
    }
    __syncthreads();

    // scores S_tile = Q @ K^T, 4 key-blocks of 16
    f32x4 sc[4];
#pragma unroll
    for (int kb = 0; kb < 4; ++kb) {
      const unsigned short* kp = K + ((size_t)n * S + s0 + kb * 16 + l16) * 256 + h * 64;
      bf16x8 kf0 = *(const bf16x8*)(kp + quad * 8);
      bf16x8 kf1 = *(const bf16x8*)(kp + 32 + quad * 8);
      f32x4 z = (f32x4){0.f, 0.f, 0.f, 0.f};
      z = __builtin_amdgcn_mfma_f32_16x16x32_bf16(qa0, kf0, z, 0, 0, 0);
      z = __builtin_amdgcn_mfma_f32_16x16x32_bf16(qa1, kf1, z, 0, 0, 0);
      sc[kb] = z;
    }

    // online softmax (rows owned by this wave; reduce across 16 lanes of quad)
    float alpha[4];
#pragma unroll
    for (int r = 0; r < 4; ++r) {
      float mx = fmaxf(fmaxf(sc[0][r], sc[1][r]), fmaxf(sc[2][r], sc[3][r])) * 0.125f;
      mx = fmaxf(mx, __shfl_xor(mx, 1));
      mx = fmaxf(mx, __shfl_xor(mx, 2));
      mx = fmaxf(mx, __shfl_xor(mx, 4));
      mx = fmaxf(mx, __shfl_xor(mx, 8));
      float mn = fmaxf(m_[r], mx);
      alpha[r] = __expf(m_[r] - mn);
      m_[r] = mn;
      float rs = 0.f;
#pragma unroll
      for (int kb = 0; kb < 4; ++kb) {
        float p = __expf(sc[kb][r] * 0.125f - mn);
        sc[kb][r] = p;
        rs += p;
      }
      rs += __shfl_xor(rs, 1);
      rs += __shfl_xor(rs, 2);
      rs += __shfl_xor(rs, 4);
      rs += __shfl_xor(rs, 8);
      l_[r] = l_[r] * alpha[r] + rs;
    }
#pragma unroll
    for (int nb = 0; nb < 4; ++nb)
#pragma unroll
      for (int r = 0; r < 4; ++r) acc[nb][r] *= alpha[r];

    // P: C-layout -> LDS -> A-layout (same wave, no barrier needed)
#pragma unroll
    for (int kb = 0; kb < 4; ++kb)
#pragma unroll
      for (int r = 0; r < 4; ++r)
        Pl[wq][quad * 4 + r][kb * 16 + l16] = f2b(sc[kb][r]);

    bf16x8 pa0 = *(const bf16x8*)&Pl[wq][l16][quad * 8];
    bf16x8 pa1 = *(const bf16x8*)&Pl[wq][l16][32 + quad * 8];
#pragma unroll
    for (int nb = 0; nb < 4; ++nb) {
      bf16x8 vb0 = *(const bf16x8*)&Vt[nb * 16 + l16][quad * 8];
      bf16x8 vb1 = *(const bf16x8*)&Vt[nb * 16 + l16][32 + quad * 8];
      acc[nb] = __builtin_amdgcn_mfma_f32_16x16x32_bf16(pa0, vb0, acc[nb], 0, 0, 0);
      acc[nb] = __builtin_amdgcn_mfma_f32_16x16x32_bf16(pa1, vb1, acc[nb], 0, 0, 0);
    }
  }

  // epilogue: O / l
#pragma unroll
  for (int r = 0; r < 4; ++r) {
    float inv = 1.f / l_[r];
    const size_t orow = (size_t)(n * L + q0 + wq * 16 + quad * 4 + r) * 256 + h * 64;
#pragma unroll
    for (int nb = 0; nb < 4; ++nb)
      O[orow + nb * 16 + l16] = f2b(acc[nb][r] * inv);
  }
}

// ---------------- LayerNorm over 256 (no affine) ----------------------------
__device__ __forceinline__ void row_stats(float4 v, float& mean, float& inv) {
  float s  = v.x + v.y + v.z + v.w;
  float s2 = fmaf(v.x, v.x, fmaf(v.y, v.y, fmaf(v.z, v.z, v.w * v.w)));
#pragma unroll
  for (int off = 32; off >= 1; off >>= 1) {
    s  += __shfl_xor(s,  off, 64);
    s2 += __shfl_xor(s2, off, 64);
  }
  mean = s * (1.f / 256.f);
  float var = s2 * (1.f / 256.f) - mean * mean;
  inv = rsqrtf(var + 1e-5f);
}

__device__ __forceinline__ float4 ld_bf4(const unsigned short* p, size_t i) {
  ushort4 u = ((const ushort4*)p)[i];
  float4 f; f.x = b2f(u.x); f.y = b2f(u.y); f.z = b2f(u.z); f.w = b2f(u.w);
  return f;
}

// msg = LN(t1), bf16 -> bf16
__global__ __launch_bounds__(64) void k_ln_b(unsigned short* __restrict__ dst,
                                             const unsigned short* __restrict__ src) {
  const size_t row = blockIdx.x;
  const int t = threadIdx.x;
  float4 v = ld_bf4(src + row * 256, t);
  float mean, inv; row_stats(v, mean, inv);
  ushort4 u;
  u.x = f2b((v.x - mean) * inv); u.y = f2b((v.y - mean) * inv);
  u.z = f2b((v.z - mean) * inv); u.w = f2b((v.w - mean) * inv);
  ((ushort4*)(dst + row * 256))[t] = u;
}

// x = x + LN(t3): f32 master + bf16 mirror
__global__ __launch_bounds__(64) void k_lnadd(float* __restrict__ xF,
                                              unsigned short* __restrict__ xB,
                                              const unsigned short* __restrict__ t3) {
  const size_t row = blockIdx.x;
  const int t = threadIdx.x;
  float4 v = ld_bf4(t3 + row * 256, t);
  float mean, inv; row_stats(v, mean, inv);
  float4 xv = ((const float4*)(xF + row * 256))[t];
  float4 r;
  r.x = xv.x + (v.x - mean) * inv; r.y = xv.y + (v.y - mean) * inv;
  r.z = xv.z + (v.z - mean) * inv; r.w = xv.w + (v.w - mean) * inv;
  ((float4*)(xF + row * 256))[t] = r;
  ushort4 u; u.x = f2b(r.x); u.y = f2b(r.y); u.z = f2b(r.z); u.w = f2b(r.w);
  ((ushort4*)(xB + row * 256))[t] = u;
}

// out = x + LN(t3), x bf16, out dtype per flag
__global__ __launch_bounds__(64) void k_lnadd_out(void* __restrict__ out, size_t off,
                                                  const unsigned short* __restrict__ xB,
                                                  const unsigned short* __restrict__ t3,
                                                  const int* __restrict__ flag) {
  const size_t row = blockIdx.x;
  const int t = threadIdx.x;
  float4 v = ld_bf4(t3 + row * 256, t);
  float mean, inv; row_stats(v, mean, inv);
  float4 xv = ld_bf4(xB + row * 256, t);
  float4 r;
  r.x = xv.x + (v.x - mean) * inv; r.y = xv.y + (v.y - mean) * inv;
  r.z = xv.z + (v.z - mean) * inv; r.w = xv.w + (v.w - mean) * inv;
  if (*flag) {
    ushort4 u; u.x = f2b(r.x); u.y = f2b(r.y); u.z = f2b(r.z); u.w = f2b(r.w);
    ((ushort4*)((unsigned short*)out + off + row * 256))[t] = u;
  } else {
    ((float4*)((float*)out + off + row * 256))[t] = r;
  }
}

// ---------------- semantic gather (index 2048 -> zeros) ---------------------
__global__ __launch_bounds__(64) void k_gather_b(unsigned short* __restrict__ dst,
                                                 const float* __restrict__ srcF,
                                                 const int* __restrict__ idx) {
  const int row = blockIdx.x;         // g*512 + l
  const int g = row >> 9;
  const int b = g >> 3;               // mask_num = 8
  const int id = idx[row];
  float4 v = {0.f, 0.f, 0.f, 0.f};
  if ((unsigned)id < 2048u)
    v = ((const float4*)(srcF + ((size_t)b * 2048 + id) * 256))[threadIdx.x];
  ushort4 u; u.x = f2b(v.x); u.y = f2b(v.y); u.z = f2b(v.z); u.w = f2b(v.w);
  ((ushort4*)(dst + (size_t)row * 256))[threadIdx.x] = u;
}

// ---------------------------------------------------------------------------
extern "C" void kernel_launch(void* const* d_in, const int* in_sizes, int n_in,
                              void* d_out, int out_size, void* d_ws, size_t ws_size,
                              hipStream_t stream) {
  const void* src_feat = d_in[0];
  const void* tgt_feat = d_in[1];
  const int* s_sub = (const int*)d_in[6];
  const int* t_sub = (const int*)d_in[7];
  const void* src2d = d_in[11];
  const void* tgt2d = d_in[12];
  const void* dinoW = d_in[14];
  const void* qW = d_in[15];
  const void* kW = d_in[16];
  const void* vW = d_in[17];
  const void* mW = d_in[18];
  const void* w1 = d_in[19];
  const void* w2 = d_in[20];

  char* p = (char*)d_ws;
  int* dflag = (int*)p;                 p += 256;
  float* sF = (float*)p;                p += 4194304;
  float* tF = (float*)p;                p += 4194304;
  unsigned short* sB   = (unsigned short*)p; p += 2097152;
  unsigned short* tB   = (unsigned short*)p; p += 2097152;
  unsigned short* s2B  = (unsigned short*)p; p += 2097152;
  unsigned short* t2B  = (unsigned short*)p; p += 2097152;
  unsigned short* d2B  = (unsigned short*)p; p += 3145728;   // 2x2048x384
  unsigned short* sSubB = (unsigned short*)p; p += 4194304;  // 16x512x256
  unsigned short* tSubB = (unsigned short*)p; p += 4194304;
  unsigned short* qB = (unsigned short*)p;   p += 4194304;   // up to 8192x256
  unsigned short* kB = (unsigned short*)p;   p += 4194304;
  unsigned short* vB = (unsigned short*)p;   p += 4194304;
  unsigned short* oB = (unsigned short*)p;   p += 4194304;
  unsigned short* hB = (unsigned short*)p;   p += 8388608;   // 8192x512
  unsigned short* WtD  = (unsigned short*)p; p += 196608;    // 256x384
  unsigned short* WtQ  = (unsigned short*)p; p += 655360;    // 5x256x256
  unsigned short* WtK  = (unsigned short*)p; p += 655360;
  unsigned short* WtV  = (unsigned short*)p; p += 655360;
  unsigned short* WtM  = (unsigned short*)p; p += 655360;
  unsigned short* WtW1 = (unsigned short*)p; p += 2621440;   // 5x512x512
  unsigned short* WtW2 = (unsigned short*)p; p += 1310720;   // 5x256x512

  // probe dtype (qW ~ N(0, 1/16))
  k_probe<<<1, 256, 0, stream>>>(dflag, (const unsigned short*)qW, 4096);

  // weight transposes (f32-or-bf16 -> bf16 W^T)
  k_wt<<<dim3(8, 12, 1), 256, 0, stream>>>(WtD, dinoW, 384, 256, dflag);
  k_wt<<<dim3(8, 8, 5), 256, 0, stream>>>(WtQ, qW, 256, 256, dflag);
  k_wt<<<dim3(8, 8, 5), 256, 0, stream>>>(WtK, kW, 256, 256, dflag);
  k_wt<<<dim3(8, 8, 5), 256, 0, stream>>>(WtV, vW, 256, 256, dflag);
  k_wt<<<dim3(8, 8, 5), 256, 0, stream>>>(WtM, mW, 256, 256, dflag);
  k_wt<<<dim3(16, 16, 5), 256, 0, stream>>>(WtW1, w1, 512, 512, dflag);
  k_wt<<<dim3(8, 16, 5), 256, 0, stream>>>(WtW2, w2, 512, 256, dflag);

  auto gmm = [&](unsigned short* Y, const unsigned short* A1, int lda1,
                 const unsigned short* A2, int lda2, int K1,
                 const unsigned short* Wt, int Ktot, int N, int relu, int M) {
    k_gmm<<<dim3(N / 64, M / 64), 256, 0, stream>>>(Y, A1, lda1, A2, lda2, K1,
                                                    Wt, Ktot, N, relu);
  };

  auto attn = [&](int l, float* xF, unsigned short* xB, const unsigned short* srcB,
                  int bs, int L, int S, size_t outOff) {
    const int R = bs * L, Rs = bs * S;
    gmm(qB, xB,   256, xB,   256, 256, WtQ + (size_t)l * 65536, 256, 256, 0, R);
    gmm(kB, srcB, 256, srcB, 256, 256, WtK + (size_t)l * 65536, 256, 256, 0, Rs);
    gmm(vB, srcB, 256, srcB, 256, 256, WtV + (size_t)l * 65536, 256, 256, 0, Rs);
    k_attn<<<dim3(L / 64, bs * 4), 256, 0, stream>>>(oB, qB, kB, vB, L, S);
    gmm(qB, oB, 256, oB, 256, 256, WtM + (size_t)l * 65536, 256, 256, 0, R);  // t1
    k_ln_b<<<R, 64, 0, stream>>>(kB, qB);                                     // msg
    gmm(hB, xB, 256, kB, 256, 256, WtW1 + (size_t)l * 262144, 512, 512, 1, R);
    gmm(vB, hB, 512, hB, 512, 512, WtW2 + (size_t)l * 131072, 512, 256, 0, R); // t3
    if (xF) k_lnadd<<<R, 64, 0, stream>>>(xF, xB, vB);
    else    k_lnadd_out<<<R, 64, 0, stream>>>(d_out, outOff, xB, vB, dflag);
  };

  // ---- init ----
  k_load2<<<1024, 256, 0, stream>>>(sF, sB, src_feat, 262144, dflag);
  k_load2<<<1024, 256, 0, stream>>>(tF, tB, tgt_feat, 262144, dflag);
  k_loadb<<<1536, 256, 0, stream>>>(d2B, src2d, 393216, dflag);
  gmm(s2B, d2B, 384, d2B, 384, 384, WtD, 384, 256, 0, 4096);
  k_loadb<<<1536, 256, 0, stream>>>(d2B, tgt2d, 393216, dflag);
  gmm(t2B, d2B, 384, d2B, 384, 384, WtD, 384, 256, 0, 4096);

  // layer 0: self (+dino)
  k_add_dino<<<1024, 256, 0, stream>>>(sF, sB, s2B, 262144);
  k_add_dino<<<1024, 256, 0, stream>>>(tF, tB, t2B, 262144);
  attn(0, sF, sB, sB, 2, 2048, 2048, 0);
  attn(0, tF, tB, tB, 2, 2048, 2048, 0);
  // layer 1: cross (tgt uses updated src)
  attn(1, sF, sB, tB, 2, 2048, 2048, 0);
  attn(1, tF, tB, sB, 2, 2048, 2048, 0);
  // layer 2: self (+dino)
  k_add_dino<<<1024, 256, 0, stream>>>(sF, sB, s2B, 262144);
  k_add_dino<<<1024, 256, 0, stream>>>(tF, tB, t2B, 262144);
  attn(2, sF, sB, sB, 2, 2048, 2048, 0);
  attn(2, tF, tB, tB, 2, 2048, 2048, 0);
  // layer 3: cross
  attn(3, sF, sB, tB, 2, 2048, 2048, 0);
  attn(3, tF, tB, sB, 2, 2048, 2048, 0);
  // semantic gather (pad index 2048 -> zeros)
  k_gather_b<<<8192, 64, 0, stream>>>(sSubB, sF, s_sub);
  k_gather_b<<<8192, 64, 0, stream>>>(tSubB, tF, t_sub);
  // layer 4: semantic subspace cross — both use ORIGINAL subsets
  attn(4, nullptr, sSubB, tSubB, 16, 512, 512, 2097152);
  attn(4, nullptr, tSubB, sSubB, 16, 512, 512, 4194304);

  // main outputs
  k_store<<<1024, 256, 0, stream>>>(d_out, 0,       sF, 262144, dflag);
  k_store<<<1024, 256, 0, stream>>>(d_out, 1048576, tF, 262144, dflag);
}

// Round 6
// 1409.725 us; speedup vs baseline: 4.1147x; 1.3232x over previous
//
#include <hip/hip_runtime.h>
#include <hip/hip_bf16.h>
#include <cstdint>
#include <cstddef>

// ---------------------------------------------------------------------------
// SemanticTransformer forward. bf16 MFMA compute, f32 residual stream.
// Split-S flash attention (partial+combine), fused QKV gemm, templated-K gemm.
// B=2, N=2048, C=256, NHEAD=4, DH=64, D2=384, G=16, Lp=512, layers=5
// Weight W^T layer strides are in ELEMENTS: QKV=196608, M=65536, W1=262144,
// W2=131072 (round-5 bug: these were halved; fixed round 6).
// ---------------------------------------------------------------------------

typedef __attribute__((ext_vector_type(8))) short bf16x8;   // 8 bf16, 4 VGPRs
typedef __attribute__((ext_vector_type(4))) float f32x4;

__device__ __forceinline__ float b2f(unsigned short u) {
  union { unsigned int i; float f; } v; v.i = ((unsigned int)u) << 16; return v.f;
}
__device__ __forceinline__ unsigned short f2b(float f) {
  __hip_bfloat16 h = __float2bfloat16(f);
  union { __hip_bfloat16 h; unsigned short u; } v; v.h = h; return v.u;
}

// ---------------- dtype probe ----------------------------------------------
__global__ __launch_bounds__(256) void k_probe(int* __restrict__ flag,
                                               const unsigned short* __restrict__ w,
                                               int n) {
  __shared__ int ok[256];
  const int t = threadIdx.x;
  int good = 1;
  for (int i = t; i < n; i += 256) {
    float v = fabsf(b2f(w[i]));
    if (!(v < 1e3f)) good = 0;
  }
  ok[t] = good;
  __syncthreads();
  for (int s = 128; s; s >>= 1) {
    if (t < s) ok[t] &= ok[t + s];
    __syncthreads();
  }
  if (t == 0) *flag = ok[0];   // 1 = bf16 data, 0 = f32 data
}

// ---------------- input loads ----------------------------------------------
__global__ __launch_bounds__(256) void k_load2(float* __restrict__ dF,
                                               unsigned short* __restrict__ dB,
                                               const void* __restrict__ src,
                                               int n4, const int* __restrict__ flag) {
  int i = blockIdx.x * 256 + threadIdx.x;
  if (i >= n4) return;
  float4 f;
  if (*flag) {
    ushort4 u = ((const ushort4*)src)[i];
    f.x = b2f(u.x); f.y = b2f(u.y); f.z = b2f(u.z); f.w = b2f(u.w);
  } else {
    f = ((const float4*)src)[i];
  }
  ((float4*)dF)[i] = f;
  ushort4 o; o.x = f2b(f.x); o.y = f2b(f.y); o.z = f2b(f.z); o.w = f2b(f.w);
  ((ushort4*)dB)[i] = o;
}

__global__ __launch_bounds__(256) void k_loadb(unsigned short* __restrict__ dB,
                                               const void* __restrict__ src,
                                               int n4, const int* __restrict__ flag) {
  int i = blockIdx.x * 256 + threadIdx.x;
  if (i >= n4) return;
  if (*flag) {
    ((ushort4*)dB)[i] = ((const ushort4*)src)[i];
    return;
  }
  float4 f = ((const float4*)src)[i];
  ushort4 o; o.x = f2b(f.x); o.y = f2b(f.y); o.z = f2b(f.z); o.w = f2b(f.w);
  ((ushort4*)dB)[i] = o;
}

__global__ __launch_bounds__(256) void k_store(void* __restrict__ out, size_t off,
                                               const float* __restrict__ src,
                                               int n4, const int* __restrict__ flag) {
  int i = blockIdx.x * 256 + threadIdx.x;
  if (i >= n4) return;
  float4 f = ((const float4*)src)[i];
  if (*flag) {
    ushort4 u; u.x = f2b(f.x); u.y = f2b(f.y); u.z = f2b(f.z); u.w = f2b(f.w);
    ((ushort4*)((unsigned short*)out + off))[i] = u;
  } else {
    ((float4*)((float*)out + off))[i] = f;
  }
}

// dino residual: xF += addB; xB = bf16(xF)
__global__ __launch_bounds__(256) void k_add_dino(float* __restrict__ xF,
                                                  unsigned short* __restrict__ xB,
                                                  const unsigned short* __restrict__ addB,
                                                  int n4) {
  int i = blockIdx.x * 256 + threadIdx.x;
  if (i >= n4) return;
  float4 a = ((const float4*)xF)[i];
  ushort4 u = ((const ushort4*)addB)[i];
  a.x += b2f(u.x); a.y += b2f(u.y); a.z += b2f(u.z); a.w += b2f(u.w);
  ((float4*)xF)[i] = a;
  ushort4 o; o.x = f2b(a.x); o.y = f2b(a.y); o.z = f2b(a.z); o.w = f2b(a.w);
  ((ushort4*)xB)[i] = o;
}

// ---------------- weight transpose+cast: Wt[z][n][k] = W[z][k][n] ----------
__global__ __launch_bounds__(256) void k_wt(unsigned short* __restrict__ Wt,
                                            const void* __restrict__ W,
                                            int K, int N, int zStride,
                                            const int* __restrict__ flag) {
  __shared__ float tile[32][33];
  const int isbf = *flag;
  const int z = blockIdx.z;
  const unsigned short* Wb = (const unsigned short*)W + (size_t)z * K * N;
  const float* Wf = (const float*)W + (size_t)z * K * N;
  unsigned short* Wo = Wt + (size_t)z * zStride;
  const int nx = blockIdx.x * 32, ky = blockIdx.y * 32;
  const int tx = threadIdx.x & 31, ty = threadIdx.x >> 5;  // ty 0..7
#pragma unroll
  for (int i = 0; i < 4; ++i) {
    int k = ky + ty + i * 8;
    float v = isbf ? b2f(Wb[(size_t)k * N + nx + tx]) : Wf[(size_t)k * N + nx + tx];
    tile[ty + i * 8][tx] = v;
  }
  __syncthreads();
#pragma unroll
  for (int i = 0; i < 4; ++i) {
    int nn = ty + i * 8;
    Wo[(size_t)(nx + nn) * K + ky + tx] = f2b(tile[tx][nn]);
  }
}

// ---------------- MFMA GEMM, compile-time K --------------------------------
// Y[row][colOff + n] = relu?( A[row] @ Wt ), A concat: k<K1 from A1 else A2.
// Wt rows are W^T (length KTOT). Tile 64x64, 4 waves x 16 rows.
template<int KTOT>
__global__ __launch_bounds__(256, 4) void k_gmm(unsigned short* __restrict__ Y,
                                                int ldy, int colOff,
                                                const unsigned short* __restrict__ A1, int lda1,
                                                const unsigned short* __restrict__ A2, int lda2,
                                                int K1,
                                                const unsigned short* __restrict__ Wt,
                                                int relu) {
  const int tid = threadIdx.x;
  const int wq = tid >> 6, lane = tid & 63;
  const int l16 = lane & 15, quad = lane >> 4;
  const int n0 = blockIdx.x * 64, m0 = blockIdx.y * 64;
  const int row = m0 + wq * 16 + l16;

  f32x4 acc[4];
#pragma unroll
  for (int i = 0; i < 4; ++i) acc[i] = (f32x4){0.f, 0.f, 0.f, 0.f};

#pragma unroll
  for (int k0 = 0; k0 < KTOT; k0 += 32) {
    const unsigned short* ap = (k0 < K1)
        ? (A1 + (size_t)row * lda1 + k0)
        : (A2 + (size_t)row * lda2 + (k0 - K1));
    bf16x8 a = *(const bf16x8*)(ap + quad * 8);
#pragma unroll
    for (int nb = 0; nb < 4; ++nb) {
      bf16x8 b = *(const bf16x8*)(Wt + (size_t)(n0 + nb * 16 + l16) * KTOT + k0 + quad * 8);
      acc[nb] = __builtin_amdgcn_mfma_f32_16x16x32_bf16(a, b, acc[nb], 0, 0, 0);
    }
  }

#pragma unroll
  for (int r = 0; r < 4; ++r) {
    unsigned short* yp = Y + (size_t)(m0 + wq * 16 + quad * 4 + r) * ldy + colOff + n0;
#pragma unroll
    for (int nb = 0; nb < 4; ++nb) {
      float v = acc[nb][r];
      if (relu) v = fmaxf(v, 0.f);
      yp[nb * 16 + l16] = f2b(v);
    }
  }
}

// ---------------- split-S MFMA flash attention: partial --------------------
// QKV: rows = n*L|S + idx, cols: q at 0, k at 256, v at 512 (lda=768), head h
// at +h*64. Grid: (L/64, nh, split). One wg = 64 queries, 4 waves x 16 q.
// Pipelined: K-frags prefetched 1 tile ahead, V 2 tiles ahead into LDS dbuf.
__global__ __launch_bounds__(256, 4) void k_attn_p(float* __restrict__ pO,
                                                   float* __restrict__ pML,
                                                   const unsigned short* __restrict__ QKV,
                                                   int lda, int L, int S, int chunk) {
  __shared__ __align__(16) unsigned short Vt[2][64][72];   // V^T: [buf][dh][key]
  __shared__ __align__(16) unsigned short Pl[4][16][72];   // per-wave P: [q][key]
  const int tid = threadIdx.x;
  const int wq = tid >> 6, lane = tid & 63;
  const int l16 = lane & 15, quad = lane >> 4;
  const int q0 = blockIdx.x * 64;
  const int nh = blockIdx.y, NHt = gridDim.y;
  const int n = nh >> 2, h = nh & 3;
  const int s0 = blockIdx.z * chunk;

  const unsigned short* Kb = QKV + 256;
  const unsigned short* Vb = QKV + 512;

  const unsigned short* qp = QKV + (size_t)(n * L + q0 + wq * 16 + l16) * lda + h * 64;
  bf16x8 qa0 = *(const bf16x8*)(qp + quad * 8);
  bf16x8 qa1 = *(const bf16x8*)(qp + 32 + quad * 8);

  f32x4 acc[4];
#pragma unroll
  for (int i = 0; i < 4; ++i) acc[i] = (f32x4){0.f, 0.f, 0.f, 0.f};
  float m_[4], l_[4];
#pragma unroll
  for (int r = 0; r < 4; ++r) { m_[r] = -1e30f; l_[r] = 0.f; }

  const int sdh0 = wq * 16;   // wave stages dh rows [wq*16, +16)
  const int skey = lane;      // lane = key

  // ---- prologue: V(0) + K(0), write Vt[0], prefetch V(64) ----
  bf16x8 kf[8];
  uint4 va, vbr;
  {
    const unsigned short* vp = Vb + (size_t)(n * S + s0 + skey) * lda + h * 64 + sdh0;
    va = *(const uint4*)vp; vbr = *(const uint4*)(vp + 8);
  }
#pragma unroll
  for (int kb = 0; kb < 4; ++kb) {
    const unsigned short* kp = Kb + (size_t)(n * S + s0 + kb * 16 + l16) * lda + h * 64;
    kf[2 * kb]     = *(const bf16x8*)(kp + quad * 8);
    kf[2 * kb + 1] = *(const bf16x8*)(kp + 32 + quad * 8);
  }
  {
    const unsigned short* p0 = (const unsigned short*)&va;
    const unsigned short* p1 = (const unsigned short*)&vbr;
#pragma unroll
    for (int i = 0; i < 8; ++i) Vt[0][sdh0 + i][skey] = p0[i];
#pragma unroll
    for (int i = 0; i < 8; ++i) Vt[0][sdh0 + 8 + i][skey] = p1[i];
  }
  if (chunk > 64) {
    const unsigned short* vp = Vb + (size_t)(n * S + s0 + 64 + skey) * lda + h * 64 + sdh0;
    va = *(const uint4*)vp; vbr = *(const uint4*)(vp + 8);
  }
  __syncthreads();

  int cur = 0;
  for (int t = 0; t < chunk; t += 64) {
    // QK^T with current K fragments
    f32x4 sc[4];
#pragma unroll
    for (int kb = 0; kb < 4; ++kb) {
      f32x4 z = (f32x4){0.f, 0.f, 0.f, 0.f};
      z = __builtin_amdgcn_mfma_f32_16x16x32_bf16(qa0, kf[2 * kb], z, 0, 0, 0);
      z = __builtin_amdgcn_mfma_f32_16x16x32_bf16(qa1, kf[2 * kb + 1], z, 0, 0, 0);
      sc[kb] = z;
    }
    // prefetch K(t+64)
    {
      int tn = t + 64; if (tn >= chunk) tn = t;
#pragma unroll
      for (int kb = 0; kb < 4; ++kb) {
        const unsigned short* kp = Kb + (size_t)(n * S + s0 + tn + kb * 16 + l16) * lda + h * 64;
        kf[2 * kb]     = *(const bf16x8*)(kp + quad * 8);
        kf[2 * kb + 1] = *(const bf16x8*)(kp + 32 + quad * 8);
      }
    }
    // online softmax (quad owns 4 rows; reduce over the 16 l16 lanes)
    float alpha[4];
#pragma unroll
    for (int r = 0; r < 4; ++r) {
      float mx = fmaxf(fmaxf(sc[0][r], sc[1][r]), fmaxf(sc[2][r], sc[3][r])) * 0.125f;
      mx = fmaxf(mx, __shfl_xor(mx, 1));
      mx = fmaxf(mx, __shfl_xor(mx, 2));
      mx = fmaxf(mx, __shfl_xor(mx, 4));
      mx = fmaxf(mx, __shfl_xor(mx, 8));
      float mn = fmaxf(m_[r], mx);
      alpha[r] = __expf(m_[r] - mn);
      m_[r] = mn;
      float rs = 0.f;
#pragma unroll
      for (int kb = 0; kb < 4; ++kb) {
        float pv = __expf(sc[kb][r] * 0.125f - mn);
        sc[kb][r] = pv;
        rs += pv;
      }
      rs += __shfl_xor(rs, 1);
      rs += __shfl_xor(rs, 2);
      rs += __shfl_xor(rs, 4);
      rs += __shfl_xor(rs, 8);
      l_[r] = l_[r] * alpha[r] + rs;
    }
#pragma unroll
    for (int nb = 0; nb < 4; ++nb)
#pragma unroll
      for (int r = 0; r < 4; ++r) acc[nb][r] *= alpha[r];

    // stage V^T(t+64) into the other buffer (disjoint from Vt[cur] readers)
    if (t + 64 < chunk) {
      const unsigned short* p0 = (const unsigned short*)&va;
      const unsigned short* p1 = (const unsigned short*)&vbr;
#pragma unroll
      for (int i = 0; i < 8; ++i) Vt[cur ^ 1][sdh0 + i][skey] = p0[i];
#pragma unroll
      for (int i = 0; i < 8; ++i) Vt[cur ^ 1][sdh0 + 8 + i][skey] = p1[i];
    }
    // prefetch V(t+128)
    if (t + 128 < chunk) {
      const unsigned short* vp = Vb + (size_t)(n * S + s0 + t + 128 + skey) * lda + h * 64 + sdh0;
      va = *(const uint4*)vp; vbr = *(const uint4*)(vp + 8);
    }

    // P: C-layout -> per-wave LDS -> A-layout
#pragma unroll
    for (int kb = 0; kb < 4; ++kb)
#pragma unroll
      for (int r = 0; r < 4; ++r)
        Pl[wq][quad * 4 + r][kb * 16 + l16] = f2b(sc[kb][r]);

    bf16x8 pa0 = *(const bf16x8*)&Pl[wq][l16][quad * 8];
    bf16x8 pa1 = *(const bf16x8*)&Pl[wq][l16][32 + quad * 8];
#pragma unroll
    for (int nb = 0; nb < 4; ++nb) {
      bf16x8 vb0 = *(const bf16x8*)&Vt[cur][nb * 16 + l16][quad * 8];
      bf16x8 vb1 = *(const bf16x8*)&Vt[cur][nb * 16 + l16][32 + quad * 8];
      acc[nb] = __builtin_amdgcn_mfma_f32_16x16x32_bf16(pa0, vb0, acc[nb], 0, 0, 0);
      acc[nb] = __builtin_amdgcn_mfma_f32_16x16x32_bf16(pa1, vb1, acc[nb], 0, 0, 0);
    }
    __syncthreads();   // all Vt[cur^1] writes done; all Vt[cur] reads done
    cur ^= 1;
  }

  // epilogue: f32 partials + (m, l)
#pragma unroll
  for (int r = 0; r < 4; ++r) {
    const int row = q0 + wq * 16 + quad * 4 + r;
    const size_t prow = ((size_t)(blockIdx.z * NHt + nh) * L + row) * 64;
#pragma unroll
    for (int nb = 0; nb < 4; ++nb) pO[prow + nb * 16 + l16] = acc[nb][r];
    if (l16 == 0) {
      float* pml = pML + ((size_t)(blockIdx.z * NHt + nh) * L + row) * 2;
      pml[0] = m_[r]; pml[1] = l_[r];
    }
  }
}

// combine: 256 threads = 64 queries x 4 dim-quarters; O bf16 (row stride 256)
__global__ __launch_bounds__(256) void k_attn_c(unsigned short* __restrict__ O,
                                                const float* __restrict__ pO,
                                                const float* __restrict__ pML,
                                                int L, int split) {
  const int tid = threadIdx.x;
  const int q = blockIdx.x * 64 + (tid >> 2);
  const int part = tid & 3;
  const int nh = blockIdx.y, NHt = gridDim.y;
  const int n = nh >> 2, h = nh & 3;

  float M = -1e30f;
  for (int sp = 0; sp < split; ++sp)
    M = fmaxf(M, pML[(((size_t)sp * NHt + nh) * L + q) * 2]);

  float4 acc[4];
#pragma unroll
  for (int i = 0; i < 4; ++i) { acc[i].x = 0.f; acc[i].y = 0.f; acc[i].z = 0.f; acc[i].w = 0.f; }
  float lsum = 0.f;
  for (int sp = 0; sp < split; ++sp) {
    const float* pml = pML + (((size_t)sp * NHt + nh) * L + q) * 2;
    float e = __expf(pml[0] - M);
    lsum = fmaf(pml[1], e, lsum);
    const float4* po = (const float4*)(pO + (((size_t)sp * NHt + nh) * L + q) * 64 + part * 16);
#pragma unroll
    for (int i = 0; i < 4; ++i) {
      float4 v = po[i];
      acc[i].x = fmaf(v.x, e, acc[i].x);
      acc[i].y = fmaf(v.y, e, acc[i].y);
      acc[i].z = fmaf(v.z, e, acc[i].z);
      acc[i].w = fmaf(v.w, e, acc[i].w);
    }
  }
  float inv = 1.0f / lsum;
  unsigned short* op = O + ((size_t)(n * L + q)) * 256 + h * 64 + part * 16;
#pragma unroll
  for (int i = 0; i < 4; ++i) {
    ushort4 u;
    u.x = f2b(acc[i].x * inv); u.y = f2b(acc[i].y * inv);
    u.z = f2b(acc[i].z * inv); u.w = f2b(acc[i].w * inv);
    ((ushort4*)op)[i] = u;
  }
}

// ---------------- LayerNorm over 256 (no affine) ----------------------------
__device__ __forceinline__ void row_stats(float4 v, float& mean, float& inv) {
  float s  = v.x + v.y + v.z + v.w;
  float s2 = fmaf(v.x, v.x, fmaf(v.y, v.y, fmaf(v.z, v.z, v.w * v.w)));
#pragma unroll
  for (int off = 32; off >= 1; off >>= 1) {
    s  += __shfl_xor(s,  off, 64);
    s2 += __shfl_xor(s2, off, 64);
  }
  mean = s * (1.f / 256.f);
  float var = s2 * (1.f / 256.f) - mean * mean;
  inv = rsqrtf(var + 1e-5f);
}

__device__ __forceinline__ float4 ld_bf4(const unsigned short* p, size_t i) {
  ushort4 u = ((const ushort4*)p)[i];
  float4 f; f.x = b2f(u.x); f.y = b2f(u.y); f.z = b2f(u.z); f.w = b2f(u.w);
  return f;
}

__global__ __launch_bounds__(64) void k_ln_b(unsigned short* __restrict__ dst,
                                             const unsigned short* __restrict__ src) {
  const size_t row = blockIdx.x;
  const int t = threadIdx.x;
  float4 v = ld_bf4(src + row * 256, t);
  float mean, inv; row_stats(v, mean, inv);
  ushort4 u;
  u.x = f2b((v.x - mean) * inv); u.y = f2b((v.y - mean) * inv);
  u.z = f2b((v.z - mean) * inv); u.w = f2b((v.w - mean) * inv);
  ((ushort4*)(dst + row * 256))[t] = u;
}

__global__ __launch_bounds__(64) void k_lnadd(float* __restrict__ xF,
                                              unsigned short* __restrict__ xB,
                                              const unsigned short* __restrict__ t3) {
  const size_t row = blockIdx.x;
  const int t = threadIdx.x;
  float4 v = ld_bf4(t3 + row * 256, t);
  float mean, inv; row_stats(v, mean, inv);
  float4 xv = ((const float4*)(xF + row * 256))[t];
  float4 r;
  r.x = xv.x + (v.x - mean) * inv; r.y = xv.y + (v.y - mean) * inv;
  r.z = xv.z + (v.z - mean) * inv; r.w = xv.w + (v.w - mean) * inv;
  ((float4*)(xF + row * 256))[t] = r;
  ushort4 u; u.x = f2b(r.x); u.y = f2b(r.y); u.z = f2b(r.z); u.w = f2b(r.w);
  ((ushort4*)(xB + row * 256))[t] = u;
}

__global__ __launch_bounds__(64) void k_lnadd_out(void* __restrict__ out, size_t off,
                                                  const unsigned short* __restrict__ xB,
                                                  const unsigned short* __restrict__ t3,
                                                  const int* __restrict__ flag) {
  const size_t row = blockIdx.x;
  const int t = threadIdx.x;
  float4 v = ld_bf4(t3 + row * 256, t);
  float mean, inv; row_stats(v, mean, inv);
  float4 xv = ld_bf4(xB + row * 256, t);
  float4 r;
  r.x = xv.x + (v.x - mean) * inv; r.y = xv.y + (v.y - mean) * inv;
  r.z = xv.z + (v.z - mean) * inv; r.w = xv.w + (v.w - mean) * inv;
  if (*flag) {
    ushort4 u; u.x = f2b(r.x); u.y = f2b(r.y); u.z = f2b(r.z); u.w = f2b(r.w);
    ((ushort4*)((unsigned short*)out + off + row * 256))[t] = u;
  } else {
    ((float4*)((float*)out + off + row * 256))[t] = r;
  }
}

// ---------------- semantic gather (index 2048 -> zeros) ---------------------
__global__ __launch_bounds__(64) void k_gather_b(unsigned short* __restrict__ dst,
                                                 const float* __restrict__ srcF,
                                                 const int* __restrict__ idx) {
  const int row = blockIdx.x;         // g*512 + l
  const int g = row >> 9;
  const int b = g >> 3;               // mask_num = 8
  const int id = idx[row];
  float4 v = {0.f, 0.f, 0.f, 0.f};
  if ((unsigned)id < 2048u)
    v = ((const float4*)(srcF + ((size_t)b * 2048 + id) * 256))[threadIdx.x];
  ushort4 u; u.x = f2b(v.x); u.y = f2b(v.y); u.z = f2b(v.z); u.w = f2b(v.w);
  ((ushort4*)(dst + (size_t)row * 256))[threadIdx.x] = u;
}

// ---------------------------------------------------------------------------
extern "C" void kernel_launch(void* const* d_in, const int* in_sizes, int n_in,
                              void* d_out, int out_size, void* d_ws, size_t ws_size,
                              hipStream_t stream) {
  const void* src_feat = d_in[0];
  const void* tgt_feat = d_in[1];
  const int* s_sub = (const int*)d_in[6];
  const int* t_sub = (const int*)d_in[7];
  const void* src2d = d_in[11];
  const void* tgt2d = d_in[12];
  const void* dinoW = d_in[14];
  const void* qW = d_in[15];
  const void* kW = d_in[16];
  const void* vW = d_in[17];
  const void* mW = d_in[18];
  const void* w1 = d_in[19];
  const void* w2 = d_in[20];

  char* p = (char*)d_ws;
  int* dflag = (int*)p;                       p += 256;
  float* sF = (float*)p;                      p += 4194304;
  float* tF = (float*)p;                      p += 4194304;
  unsigned short* sB    = (unsigned short*)p; p += 2097152;
  unsigned short* tB    = (unsigned short*)p; p += 2097152;
  unsigned short* s2B   = (unsigned short*)p; p += 2097152;
  unsigned short* t2B   = (unsigned short*)p; p += 2097152;
  unsigned short* d2B   = (unsigned short*)p; p += 3145728;   // 4096x384
  unsigned short* sSubB = (unsigned short*)p; p += 4194304;   // 8192x256
  unsigned short* tSubB = (unsigned short*)p; p += 4194304;
  unsigned short* qkvB  = (unsigned short*)p; p += 12582912;  // 8192x768
  unsigned short* oB    = (unsigned short*)p; p += 4194304;   // 8192x256
  unsigned short* t1B   = (unsigned short*)p; p += 4194304;
  unsigned short* msgB  = (unsigned short*)p; p += 4194304;
  unsigned short* hB    = (unsigned short*)p; p += 8388608;   // 8192x512
  unsigned short* t3B   = (unsigned short*)p; p += 4194304;
  unsigned short* WtD   = (unsigned short*)p; p += 196608;    // 256x384
  unsigned short* WtQKV = (unsigned short*)p; p += 1966080;   // 5x768x256
  unsigned short* WtM   = (unsigned short*)p; p += 655360;    // 5x256x256
  unsigned short* WtW1  = (unsigned short*)p; p += 2621440;   // 5x512x512
  unsigned short* WtW2  = (unsigned short*)p; p += 1310720;   // 5x256x512
  float* pO  = (float*)p;                     p += 16777216;  // 4*8*2048*64 f32
  float* pML = (float*)p;                     p += 524288;
  // total ~89 MB

  // probe dtype (qW ~ N(0, 1/16))
  k_probe<<<1, 256, 0, stream>>>(dflag, (const unsigned short*)qW, 4096);

  // weight transposes (f32-or-bf16 -> bf16 W^T); QKV packed per layer (768 rows)
  // zStride is in ELEMENTS (ushorts)
  k_wt<<<dim3(8, 12, 1), 256, 0, stream>>>(WtD, dinoW, 384, 256, 0, dflag);
  k_wt<<<dim3(8, 8, 5), 256, 0, stream>>>(WtQKV,          qW, 256, 256, 196608, dflag);
  k_wt<<<dim3(8, 8, 5), 256, 0, stream>>>(WtQKV + 65536,  kW, 256, 256, 196608, dflag);
  k_wt<<<dim3(8, 8, 5), 256, 0, stream>>>(WtQKV + 131072, vW, 256, 256, 196608, dflag);
  k_wt<<<dim3(8, 8, 5), 256, 0, stream>>>(WtM, mW, 256, 256, 65536, dflag);
  k_wt<<<dim3(16, 16, 5), 256, 0, stream>>>(WtW1, w1, 512, 512, 262144, dflag);
  k_wt<<<dim3(8, 16, 5), 256, 0, stream>>>(WtW2, w2, 512, 256, 131072, dflag);

  auto attn = [&](int l, float* xF, unsigned short* xB, const unsigned short* srcB,
                  int bs, int L, int S, int split, size_t outOff) {
    const int R = bs * L;
    // layer strides in ELEMENTS: QKV 196608, M 65536, W1 262144, W2 131072
    const unsigned short* Wqkv = WtQKV + (size_t)l * 196608;
    if (xB == srcB) {
      k_gmm<256><<<dim3(12, R / 64), 256, 0, stream>>>(qkvB, 768, 0, xB, 256, xB, 256,
                                                       256, Wqkv, 0);
    } else {
      k_gmm<256><<<dim3(4, R / 64), 256, 0, stream>>>(qkvB, 768, 0, xB, 256, xB, 256,
                                                      256, Wqkv, 0);
      k_gmm<256><<<dim3(8, R / 64), 256, 0, stream>>>(qkvB, 768, 256, srcB, 256, srcB, 256,
                                                      256, Wqkv + 65536, 0);
    }
    const int chunk = S / split;
    k_attn_p<<<dim3(L / 64, bs * 4, split), 256, 0, stream>>>(pO, pML, qkvB, 768, L, S, chunk);
    k_attn_c<<<dim3(L / 64, bs * 4), 256, 0, stream>>>(oB, pO, pML, L, split);
    k_gmm<256><<<dim3(4, R / 64), 256, 0, stream>>>(t1B, 256, 0, oB, 256, oB, 256,
                                                    256, WtM + (size_t)l * 65536, 0);
    k_ln_b<<<R, 64, 0, stream>>>(msgB, t1B);
    k_gmm<512><<<dim3(8, R / 64), 256, 0, stream>>>(hB, 512, 0, xB, 256, msgB, 256,
                                                    256, WtW1 + (size_t)l * 262144, 1);
    k_gmm<512><<<dim3(4, R / 64), 256, 0, stream>>>(t3B, 256, 0, hB, 512, hB, 512,
                                                    512, WtW2 + (size_t)l * 131072, 0);
    if (xF) k_lnadd<<<R, 64, 0, stream>>>(xF, xB, t3B);
    else    k_lnadd_out<<<R, 64, 0, stream>>>(d_out, outOff, xB, t3B, dflag);
  };

  // ---- init ----
  k_load2<<<1024, 256, 0, stream>>>(sF, sB, src_feat, 262144, dflag);
  k_load2<<<1024, 256, 0, stream>>>(tF, tB, tgt_feat, 262144, dflag);
  k_loadb<<<1536, 256, 0, stream>>>(d2B, src2d, 393216, dflag);
  k_gmm<384><<<dim3(4, 64), 256, 0, stream>>>(s2B, 256, 0, d2B, 384, d2B, 384, 384, WtD, 0);
  k_loadb<<<1536, 256, 0, stream>>>(d2B, tgt2d, 393216, dflag);
  k_gmm<384><<<dim3(4, 64), 256, 0, stream>>>(t2B, 256, 0, d2B, 384, d2B, 384, 384, WtD, 0);

  // layer 0: self (+dino)
  k_add_dino<<<1024, 256, 0, stream>>>(sF, sB, s2B, 262144);
  k_add_dino<<<1024, 256, 0, stream>>>(tF, tB, t2B, 262144);
  attn(0, sF, sB, sB, 2, 2048, 2048, 4, 0);
  attn(0, tF, tB, tB, 2, 2048, 2048, 4, 0);
  // layer 1: cross (tgt uses updated src)
  attn(1, sF, sB, tB, 2, 2048, 2048, 4, 0);
  attn(1, tF, tB, sB, 2, 2048, 2048, 4, 0);
  // layer 2: self (+dino)
  k_add_dino<<<1024, 256, 0, stream>>>(sF, sB, s2B, 262144);
  k_add_dino<<<1024, 256, 0, stream>>>(tF, tB, t2B, 262144);
  attn(2, sF, sB, sB, 2, 2048, 2048, 4, 0);
  attn(2, tF, tB, tB, 2, 2048, 2048, 4, 0);
  // layer 3: cross
  attn(3, sF, sB, tB, 2, 2048, 2048, 4, 0);
  attn(3, tF, tB, sB, 2, 2048, 2048, 4, 0);
  // semantic gather (pad index 2048 -> zeros)
  k_gather_b<<<8192, 64, 0, stream>>>(sSubB, sF, s_sub);
  k_gather_b<<<8192, 64, 0, stream>>>(tSubB, tF, t_sub);
  // layer 4: semantic subspace cross — both use ORIGINAL subsets
  attn(4, nullptr, sSubB, tSubB, 16, 512, 512, 2, 2097152);
  attn(4, nullptr, tSubB, sSubB, 16, 512, 512, 2, 4194304);

  // main outputs
  k_store<<<1024, 256, 0, stream>>>(d_out, 0,       sF, 262144, dflag);
  k_store<<<1024, 256, 0, stream>>>(d_out, 1048576, tF, 262144, dflag);
}

// Round 7
// 1391.191 us; speedup vs baseline: 4.1695x; 1.0133x over previous
//
#include <hip/hip_runtime.h>
#include <hip/hip_bf16.h>
#include <cstdint>
#include <cstddef>

// ---------------------------------------------------------------------------
// SemanticTransformer forward. bf16 MFMA compute, f32 residual stream.
// Round 7: transposed-score flash attention (S^T = K Q^T -> softmax in-reg,
// 2 shuffles/tile instead of 32), packed P stores, O^T epilogue transpose.
// GEMM launch_bounds (256,3) for VGPR headroom.
// B=2, N=2048, C=256, NHEAD=4, DH=64, D2=384, G=16, Lp=512, layers=5
// ---------------------------------------------------------------------------

typedef __attribute__((ext_vector_type(8))) short bf16x8;   // 8 bf16, 4 VGPRs
typedef __attribute__((ext_vector_type(4))) float f32x4;

__device__ __forceinline__ float b2f(unsigned short u) {
  union { unsigned int i; float f; } v; v.i = ((unsigned int)u) << 16; return v.f;
}
__device__ __forceinline__ unsigned short f2b(float f) {
  __hip_bfloat16 h = __float2bfloat16(f);
  union { __hip_bfloat16 h; unsigned short u; } v; v.h = h; return v.u;
}

// ---------------- dtype probe ----------------------------------------------
__global__ __launch_bounds__(256) void k_probe(int* __restrict__ flag,
                                               const unsigned short* __restrict__ w,
                                               int n) {
  __shared__ int ok[256];
  const int t = threadIdx.x;
  int good = 1;
  for (int i = t; i < n; i += 256) {
    float v = fabsf(b2f(w[i]));
    if (!(v < 1e3f)) good = 0;
  }
  ok[t] = good;
  __syncthreads();
  for (int s = 128; s; s >>= 1) {
    if (t < s) ok[t] &= ok[t + s];
    __syncthreads();
  }
  if (t == 0) *flag = ok[0];   // 1 = bf16 data, 0 = f32 data
}

// ---------------- input loads ----------------------------------------------
__global__ __launch_bounds__(256) void k_load2(float* __restrict__ dF,
                                               unsigned short* __restrict__ dB,
                                               const void* __restrict__ src,
                                               int n4, const int* __restrict__ flag) {
  int i = blockIdx.x * 256 + threadIdx.x;
  if (i >= n4) return;
  float4 f;
  if (*flag) {
    ushort4 u = ((const ushort4*)src)[i];
    f.x = b2f(u.x); f.y = b2f(u.y); f.z = b2f(u.z); f.w = b2f(u.w);
  } else {
    f = ((const float4*)src)[i];
  }
  ((float4*)dF)[i] = f;
  ushort4 o; o.x = f2b(f.x); o.y = f2b(f.y); o.z = f2b(f.z); o.w = f2b(f.w);
  ((ushort4*)dB)[i] = o;
}

__global__ __launch_bounds__(256) void k_loadb(unsigned short* __restrict__ dB,
                                               const void* __restrict__ src,
                                               int n4, const int* __restrict__ flag) {
  int i = blockIdx.x * 256 + threadIdx.x;
  if (i >= n4) return;
  if (*flag) {
    ((ushort4*)dB)[i] = ((const ushort4*)src)[i];
    return;
  }
  float4 f = ((const float4*)src)[i];
  ushort4 o; o.x = f2b(f.x); o.y = f2b(f.y); o.z = f2b(f.z); o.w = f2b(f.w);
  ((ushort4*)dB)[i] = o;
}

__global__ __launch_bounds__(256) void k_store(void* __restrict__ out, size_t off,
                                               const float* __restrict__ src,
                                               int n4, const int* __restrict__ flag) {
  int i = blockIdx.x * 256 + threadIdx.x;
  if (i >= n4) return;
  float4 f = ((const float4*)src)[i];
  if (*flag) {
    ushort4 u; u.x = f2b(f.x); u.y = f2b(f.y); u.z = f2b(f.z); u.w = f2b(f.w);
    ((ushort4*)((unsigned short*)out + off))[i] = u;
  } else {
    ((float4*)((float*)out + off))[i] = f;
  }
}

// dino residual: xF += addB; xB = bf16(xF)
__global__ __launch_bounds__(256) void k_add_dino(float* __restrict__ xF,
                                                  unsigned short* __restrict__ xB,
                                                  const unsigned short* __restrict__ addB,
                                                  int n4) {
  int i = blockIdx.x * 256 + threadIdx.x;
  if (i >= n4) return;
  float4 a = ((const float4*)xF)[i];
  ushort4 u = ((const ushort4*)addB)[i];
  a.x += b2f(u.x); a.y += b2f(u.y); a.z += b2f(u.z); a.w += b2f(u.w);
  ((float4*)xF)[i] = a;
  ushort4 o; o.x = f2b(a.x); o.y = f2b(a.y); o.z = f2b(a.z); o.w = f2b(a.w);
  ((ushort4*)xB)[i] = o;
}

// ---------------- weight transpose+cast: Wt[z][n][k] = W[z][k][n] ----------
__global__ __launch_bounds__(256) void k_wt(unsigned short* __restrict__ Wt,
                                            const void* __restrict__ W,
                                            int K, int N, int zStride,
                                            const int* __restrict__ flag) {
  __shared__ float tile[32][33];
  const int isbf = *flag;
  const int z = blockIdx.z;
  const unsigned short* Wb = (const unsigned short*)W + (size_t)z * K * N;
  const float* Wf = (const float*)W + (size_t)z * K * N;
  unsigned short* Wo = Wt + (size_t)z * zStride;
  const int nx = blockIdx.x * 32, ky = blockIdx.y * 32;
  const int tx = threadIdx.x & 31, ty = threadIdx.x >> 5;  // ty 0..7
#pragma unroll
  for (int i = 0; i < 4; ++i) {
    int k = ky + ty + i * 8;
    float v = isbf ? b2f(Wb[(size_t)k * N + nx + tx]) : Wf[(size_t)k * N + nx + tx];
    tile[ty + i * 8][tx] = v;
  }
  __syncthreads();
#pragma unroll
  for (int i = 0; i < 4; ++i) {
    int nn = ty + i * 8;
    Wo[(size_t)(nx + nn) * K + ky + tx] = f2b(tile[tx][nn]);
  }
}

// ---------------- MFMA GEMM, compile-time K --------------------------------
// Y[row][colOff + n] = relu?( A[row] @ Wt ), A concat: k<K1 from A1 else A2.
// Wt rows are W^T (length KTOT). Tile 64x64, 4 waves x 16 rows.
// (256,3): grids here are <=768 wgs (<=3 wg/CU anyway); VGPR cap ~170 lets the
// fully-unrolled k-loop keep loads in flight.
template<int KTOT>
__global__ __launch_bounds__(256, 3) void k_gmm(unsigned short* __restrict__ Y,
                                                int ldy, int colOff,
                                                const unsigned short* __restrict__ A1, int lda1,
                                                const unsigned short* __restrict__ A2, int lda2,
                                                int K1,
                                                const unsigned short* __restrict__ Wt,
                                                int relu) {
  const int tid = threadIdx.x;
  const int wq = tid >> 6, lane = tid & 63;
  const int l16 = lane & 15, quad = lane >> 4;
  const int n0 = blockIdx.x * 64, m0 = blockIdx.y * 64;
  const int row = m0 + wq * 16 + l16;

  f32x4 acc[4];
#pragma unroll
  for (int i = 0; i < 4; ++i) acc[i] = (f32x4){0.f, 0.f, 0.f, 0.f};

#pragma unroll
  for (int k0 = 0; k0 < KTOT; k0 += 32) {
    const unsigned short* ap = (k0 < K1)
        ? (A1 + (size_t)row * lda1 + k0)
        : (A2 + (size_t)row * lda2 + (k0 - K1));
    bf16x8 a = *(const bf16x8*)(ap + quad * 8);
#pragma unroll
    for (int nb = 0; nb < 4; ++nb) {
      bf16x8 b = *(const bf16x8*)(Wt + (size_t)(n0 + nb * 16 + l16) * KTOT + k0 + quad * 8);
      acc[nb] = __builtin_amdgcn_mfma_f32_16x16x32_bf16(a, b, acc[nb], 0, 0, 0);
    }
  }

#pragma unroll
  for (int r = 0; r < 4; ++r) {
    unsigned short* yp = Y + (size_t)(m0 + wq * 16 + quad * 4 + r) * ldy + colOff + n0;
#pragma unroll
    for (int nb = 0; nb < 4; ++nb) {
      float v = acc[nb][r];
      if (relu) v = fmaxf(v, 0.f);
      yp[nb * 16 + l16] = f2b(v);
    }
  }
}

// ---------------- split-S MFMA flash attention: partial (transposed) -------
// QKV: rows = n*L|S + idx, cols: q at 0, k at 256, v at 512 (lda=768), head h
// at +h*64. Grid: (L/64, nh, split). One wg = 64 queries, 4 waves x 16 q.
// Scores computed TRANSPOSED (S^T = K Q^T): query on lanes, keys on regs ->
// softmax is in-register + 2 cross-quad shuffles; m/l are per-lane scalars.
// PV computes O^T = V^T P; epilogue transposes O^T->O via LDS (reuses Vt).
__global__ __launch_bounds__(256, 4) void k_attn_p(float* __restrict__ pO,
                                                   float* __restrict__ pML,
                                                   const unsigned short* __restrict__ QKV,
                                                   int lda, int L, int S, int chunk) {
  __shared__ __align__(16) unsigned short Vt[2][64][72];   // V^T: [buf][dh][key]
  __shared__ __align__(16) unsigned short Ps[4][16][72];   // per-wave P: [q][key]
  const int tid = threadIdx.x;
  const int wq = tid >> 6, lane = tid & 63;
  const int l16 = lane & 15, quad = lane >> 4;
  const int q0 = blockIdx.x * 64;
  const int nh = blockIdx.y, NHt = gridDim.y;
  const int n = nh >> 2, h = nh & 3;
  const int s0 = blockIdx.z * chunk;

  const unsigned short* Kb = QKV + 256;
  const unsigned short* Vb = QKV + 512;

  // Q as B-operand: 16 queries of this wave on lanes
  const unsigned short* qp = QKV + (size_t)(n * L + q0 + wq * 16 + l16) * lda + h * 64;
  bf16x8 qa0 = *(const bf16x8*)(qp + quad * 8);
  bf16x8 qa1 = *(const bf16x8*)(qp + 32 + quad * 8);

  f32x4 acc[4];   // O^T: acc[db][r] = O^T[db*16+quad*4+r][q=l16]
#pragma unroll
  for (int i = 0; i < 4; ++i) acc[i] = (f32x4){0.f, 0.f, 0.f, 0.f};
  float m_ = -1e30f, l_ = 0.f;   // per-lane (query l16), replicated across quads

  const int sdh0 = wq * 16;   // V staging: wave wq covers dh rows [wq*16, +16)
  const int skey = lane;      // lane = key

  // ---- prologue: V(0) + K(0), write Vt[0], prefetch V(64) ----
  bf16x8 kf[8];
  uint4 va, vbr;
  {
    const unsigned short* vp = Vb + (size_t)(n * S + s0 + skey) * lda + h * 64 + sdh0;
    va = *(const uint4*)vp; vbr = *(const uint4*)(vp + 8);
  }
#pragma unroll
  for (int kb = 0; kb < 4; ++kb) {
    const unsigned short* kp = Kb + (size_t)(n * S + s0 + kb * 16 + l16) * lda + h * 64;
    kf[2 * kb]     = *(const bf16x8*)(kp + quad * 8);
    kf[2 * kb + 1] = *(const bf16x8*)(kp + 32 + quad * 8);
  }
  {
    const unsigned short* p0 = (const unsigned short*)&va;
    const unsigned short* p1 = (const unsigned short*)&vbr;
#pragma unroll
    for (int i = 0; i < 8; ++i) Vt[0][sdh0 + i][skey] = p0[i];
#pragma unroll
    for (int i = 0; i < 8; ++i) Vt[0][sdh0 + 8 + i][skey] = p1[i];
  }
  if (chunk > 64) {
    const unsigned short* vp = Vb + (size_t)(n * S + s0 + 64 + skey) * lda + h * 64 + sdh0;
    va = *(const uint4*)vp; vbr = *(const uint4*)(vp + 8);
  }
  __syncthreads();

  int cur = 0;
  for (int t = 0; t < chunk; t += 64) {
    // S^T tile = K Q^T : A=K rows (keys), B=Q rows (queries)
    // sc[kb][r] = S^T[key = kb*16 + quad*4 + r][q = l16]
    f32x4 sc[4];
#pragma unroll
    for (int kb = 0; kb < 4; ++kb) {
      f32x4 z = (f32x4){0.f, 0.f, 0.f, 0.f};
      z = __builtin_amdgcn_mfma_f32_16x16x32_bf16(kf[2 * kb], qa0, z, 0, 0, 0);
      z = __builtin_amdgcn_mfma_f32_16x16x32_bf16(kf[2 * kb + 1], qa1, z, 0, 0, 0);
      sc[kb] = z;
    }
    // prefetch K(t+64)
    {
      int tn = t + 64; if (tn >= chunk) tn = t;
#pragma unroll
      for (int kb = 0; kb < 4; ++kb) {
        const unsigned short* kp = Kb + (size_t)(n * S + s0 + tn + kb * 16 + l16) * lda + h * 64;
        kf[2 * kb]     = *(const bf16x8*)(kp + quad * 8);
        kf[2 * kb + 1] = *(const bf16x8*)(kp + 32 + quad * 8);
      }
    }
    // online softmax: in-register tree + 2 cross-quad shuffles
    f32x4 mv01, mv;
#pragma unroll
    for (int r = 0; r < 4; ++r) mv01[r] = fmaxf(sc[0][r], sc[1][r]);
#pragma unroll
    for (int r = 0; r < 4; ++r) mv[r] = fmaxf(mv01[r], fmaxf(sc[2][r], sc[3][r]));
    float mx = fmaxf(fmaxf(mv[0], mv[1]), fmaxf(mv[2], mv[3])) * 0.125f;
    mx = fmaxf(mx, __shfl_xor(mx, 16));
    mx = fmaxf(mx, __shfl_xor(mx, 32));
    float mn = fmaxf(m_, mx);
    float alpha = __expf(m_ - mn);
    m_ = mn;
    float rs = 0.f;
#pragma unroll
    for (int kb = 0; kb < 4; ++kb)
#pragma unroll
      for (int r = 0; r < 4; ++r) {
        float pv = __expf(sc[kb][r] * 0.125f - mn);
        sc[kb][r] = pv;
        rs += pv;
      }
    rs += __shfl_xor(rs, 16);
    rs += __shfl_xor(rs, 32);
    l_ = l_ * alpha + rs;
#pragma unroll
    for (int nb = 0; nb < 4; ++nb)
#pragma unroll
      for (int r = 0; r < 4; ++r) acc[nb][r] *= alpha;

    // stage V^T(t+64) into the other buffer (disjoint from Vt[cur] readers)
    if (t + 64 < chunk) {
      const unsigned short* p0 = (const unsigned short*)&va;
      const unsigned short* p1 = (const unsigned short*)&vbr;
#pragma unroll
      for (int i = 0; i < 8; ++i) Vt[cur ^ 1][sdh0 + i][skey] = p0[i];
#pragma unroll
      for (int i = 0; i < 8; ++i) Vt[cur ^ 1][sdh0 + 8 + i][skey] = p1[i];
    }
    // prefetch V(t+128)
    if (t + 128 < chunk) {
      const unsigned short* vp = Vb + (size_t)(n * S + s0 + t + 128 + skey) * lda + h * 64 + sdh0;
      va = *(const uint4*)vp; vbr = *(const uint4*)(vp + 8);
    }

    // P^T -> LDS as P[q][key]; keys quad*4+r are consecutive -> packed b64
#pragma unroll
    for (int kb = 0; kb < 4; ++kb) {
      ushort4 u;
      u.x = f2b(sc[kb][0]); u.y = f2b(sc[kb][1]);
      u.z = f2b(sc[kb][2]); u.w = f2b(sc[kb][3]);
      *(ushort4*)&Ps[wq][l16][kb * 16 + quad * 4] = u;
    }

    // O^T += V^T P : A=V^T rows (dh), B=P rows (queries)
    bf16x8 ps0 = *(const bf16x8*)&Ps[wq][l16][quad * 8];
    bf16x8 ps1 = *(const bf16x8*)&Ps[wq][l16][32 + quad * 8];
#pragma unroll
    for (int db = 0; db < 4; ++db) {
      bf16x8 vb0 = *(const bf16x8*)&Vt[cur][db * 16 + l16][quad * 8];
      bf16x8 vb1 = *(const bf16x8*)&Vt[cur][db * 16 + l16][32 + quad * 8];
      acc[db] = __builtin_amdgcn_mfma_f32_16x16x32_bf16(vb0, ps0, acc[db], 0, 0, 0);
      acc[db] = __builtin_amdgcn_mfma_f32_16x16x32_bf16(vb1, ps1, acc[db], 0, 0, 0);
    }
    __syncthreads();   // all Vt[cur^1] writes done; all Vt[cur] reads done
    cur ^= 1;
  }

  // ---- epilogue: transpose O^T -> O via LDS (reuse Vt as f32 [64][68]) ----
  float* Ot = (float*)&Vt[0][0][0];
#pragma unroll
  for (int db = 0; db < 4; ++db)
    *(f32x4*)&Ot[(size_t)(wq * 16 + l16) * 68 + db * 16 + quad * 4] = acc[db];
  __syncthreads();
#pragma unroll
  for (int i = 0; i < 16; ++i) {
    const int row = q0 + wq * 16 + i;
    pO[((size_t)(blockIdx.z * NHt + nh) * L + row) * 64 + lane] =
        Ot[(size_t)(wq * 16 + i) * 68 + lane];
  }
  if (quad == 0) {
    float* pml = pML + ((size_t)(blockIdx.z * NHt + nh) * L + q0 + wq * 16 + l16) * 2;
    pml[0] = m_; pml[1] = l_;
  }
}

// combine: 256 threads = 64 queries x 4 dim-quarters; O bf16 (row stride 256)
__global__ __launch_bounds__(256) void k_attn_c(unsigned short* __restrict__ O,
                                                const float* __restrict__ pO,
                                                const float* __restrict__ pML,
                                                int L, int split) {
  const int tid = threadIdx.x;
  const int q = blockIdx.x * 64 + (tid >> 2);
  const int part = tid & 3;
  const int nh = blockIdx.y, NHt = gridDim.y;
  const int n = nh >> 2, h = nh & 3;

  float M = -1e30f;
  for (int sp = 0; sp < split; ++sp)
    M = fmaxf(M, pML[(((size_t)sp * NHt + nh) * L + q) * 2]);

  float4 acc[4];
#pragma unroll
  for (int i = 0; i < 4; ++i) { acc[i].x = 0.f; acc[i].y = 0.f; acc[i].z = 0.f; acc[i].w = 0.f; }
  float lsum = 0.f;
  for (int sp = 0; sp < split; ++sp) {
    const float* pml = pML + (((size_t)sp * NHt + nh) * L + q) * 2;
    float e = __expf(pml[0] - M);
    lsum = fmaf(pml[1], e, lsum);
    const float4* po = (const float4*)(pO + (((size_t)sp * NHt + nh) * L + q) * 64 + part * 16);
#pragma unroll
    for (int i = 0; i < 4; ++i) {
      float4 v = po[i];
      acc[i].x = fmaf(v.x, e, acc[i].x);
      acc[i].y = fmaf(v.y, e, acc[i].y);
      acc[i].z = fmaf(v.z, e, acc[i].z);
      acc[i].w = fmaf(v.w, e, acc[i].w);
    }
  }
  float inv = 1.0f / lsum;
  unsigned short* op = O + ((size_t)(n * L + q)) * 256 + h * 64 + part * 16;
#pragma unroll
  for (int i = 0; i < 4; ++i) {
    ushort4 u;
    u.x = f2b(acc[i].x * inv); u.y = f2b(acc[i].y * inv);
    u.z = f2b(acc[i].z * inv); u.w = f2b(acc[i].w * inv);
    ((ushort4*)op)[i] = u;
  }
}

// ---------------- LayerNorm over 256 (no affine) ----------------------------
__device__ __forceinline__ void row_stats(float4 v, float& mean, float& inv) {
  float s  = v.x + v.y + v.z + v.w;
  float s2 = fmaf(v.x, v.x, fmaf(v.y, v.y, fmaf(v.z, v.z, v.w * v.w)));
#pragma unroll
  for (int off = 32; off >= 1; off >>= 1) {
    s  += __shfl_xor(s,  off, 64);
    s2 += __shfl_xor(s2, off, 64);
  }
  mean = s * (1.f / 256.f);
  float var = s2 * (1.f / 256.f) - mean * mean;
  inv = rsqrtf(var + 1e-5f);
}

__device__ __forceinline__ float4 ld_bf4(const unsigned short* p, size_t i) {
  ushort4 u = ((const ushort4*)p)[i];
  float4 f; f.x = b2f(u.x); f.y = b2f(u.y); f.z = b2f(u.z); f.w = b2f(u.w);
  return f;
}

__global__ __launch_bounds__(64) void k_ln_b(unsigned short* __restrict__ dst,
                                             const unsigned short* __restrict__ src) {
  const size_t row = blockIdx.x;
  const int t = threadIdx.x;
  float4 v = ld_bf4(src + row * 256, t);
  float mean, inv; row_stats(v, mean, inv);
  ushort4 u;
  u.x = f2b((v.x - mean) * inv); u.y = f2b((v.y - mean) * inv);
  u.z = f2b((v.z - mean) * inv); u.w = f2b((v.w - mean) * inv);
  ((ushort4*)(dst + row * 256))[t] = u;
}

__global__ __launch_bounds__(64) void k_lnadd(float* __restrict__ xF,
                                              unsigned short* __restrict__ xB,
                                              const unsigned short* __restrict__ t3) {
  const size_t row = blockIdx.x;
  const int t = threadIdx.x;
  float4 v = ld_bf4(t3 + row * 256, t);
  float mean, inv; row_stats(v, mean, inv);
  float4 xv = ((const float4*)(xF + row * 256))[t];
  float4 r;
  r.x = xv.x + (v.x - mean) * inv; r.y = xv.y + (v.y - mean) * inv;
  r.z = xv.z + (v.z - mean) * inv; r.w = xv.w + (v.w - mean) * inv;
  ((float4*)(xF + row * 256))[t] = r;
  ushort4 u; u.x = f2b(r.x); u.y = f2b(r.y); u.z = f2b(r.z); u.w = f2b(r.w);
  ((ushort4*)(xB + row * 256))[t] = u;
}

__global__ __launch_bounds__(64) void k_lnadd_out(void* __restrict__ out, size_t off,
                                                  const unsigned short* __restrict__ xB,
                                                  const unsigned short* __restrict__ t3,
                                                  const int* __restrict__ flag) {
  const size_t row = blockIdx.x;
  const int t = threadIdx.x;
  float4 v = ld_bf4(t3 + row * 256, t);
  float mean, inv; row_stats(v, mean, inv);
  float4 xv = ld_bf4(xB + row * 256, t);
  float4 r;
  r.x = xv.x + (v.x - mean) * inv; r.y = xv.y + (v.y - mean) * inv;
  r.z = xv.z + (v.z - mean) * inv; r.w = xv.w + (v.w - mean) * inv;
  if (*flag) {
    ushort4 u; u.x = f2b(r.x); u.y = f2b(r.y); u.z = f2b(r.z); u.w = f2b(r.w);
    ((ushort4*)((unsigned short*)out + off + row * 256))[t] = u;
  } else {
    ((float4*)((float*)out + off + row * 256))[t] = r;
  }
}

// ---------------- semantic gather (index 2048 -> zeros) ---------------------
__global__ __launch_bounds__(64) void k_gather_b(unsigned short* __restrict__ dst,
                                                 const float* __restrict__ srcF,
                                                 const int* __restrict__ idx) {
  const int row = blockIdx.x;         // g*512 + l
  const int g = row >> 9;
  const int b = g >> 3;               // mask_num = 8
  const int id = idx[row];
  float4 v = {0.f, 0.f, 0.f, 0.f};
  if ((unsigned)id < 2048u)
    v = ((const float4*)(srcF + ((size_t)b * 2048 + id) * 256))[threadIdx.x];
  ushort4 u; u.x = f2b(v.x); u.y = f2b(v.y); u.z = f2b(v.z); u.w = f2b(v.w);
  ((ushort4*)(dst + (size_t)row * 256))[threadIdx.x] = u;
}

// ---------------------------------------------------------------------------
extern "C" void kernel_launch(void* const* d_in, const int* in_sizes, int n_in,
                              void* d_out, int out_size, void* d_ws, size_t ws_size,
                              hipStream_t stream) {
  const void* src_feat = d_in[0];
  const void* tgt_feat = d_in[1];
  const int* s_sub = (const int*)d_in[6];
  const int* t_sub = (const int*)d_in[7];
  const void* src2d = d_in[11];
  const void* tgt2d = d_in[12];
  const void* dinoW = d_in[14];
  const void* qW = d_in[15];
  const void* kW = d_in[16];
  const void* vW = d_in[17];
  const void* mW = d_in[18];
  const void* w1 = d_in[19];
  const void* w2 = d_in[20];

  char* p = (char*)d_ws;
  int* dflag = (int*)p;                       p += 256;
  float* sF = (float*)p;                      p += 4194304;
  float* tF = (float*)p;                      p += 4194304;
  unsigned short* sB    = (unsigned short*)p; p += 2097152;
  unsigned short* tB    = (unsigned short*)p; p += 2097152;
  unsigned short* s2B   = (unsigned short*)p; p += 2097152;
  unsigned short* t2B   = (unsigned short*)p; p += 2097152;
  unsigned short* d2B   = (unsigned short*)p; p += 3145728;   // 4096x384
  unsigned short* sSubB = (unsigned short*)p; p += 4194304;   // 8192x256
  unsigned short* tSubB = (unsigned short*)p; p += 4194304;
  unsigned short* qkvB  = (unsigned short*)p; p += 12582912;  // 8192x768
  unsigned short* oB    = (unsigned short*)p; p += 4194304;   // 8192x256
  unsigned short* t1B   = (unsigned short*)p; p += 4194304;
  unsigned short* msgB  = (unsigned short*)p; p += 4194304;
  unsigned short* hB    = (unsigned short*)p; p += 8388608;   // 8192x512
  unsigned short* t3B   = (unsigned short*)p; p += 4194304;
  unsigned short* WtD   = (unsigned short*)p; p += 196608;    // 256x384
  unsigned short* WtQKV = (unsigned short*)p; p += 1966080;   // 5x768x256
  unsigned short* WtM   = (unsigned short*)p; p += 655360;    // 5x256x256
  unsigned short* WtW1  = (unsigned short*)p; p += 2621440;   // 5x512x512
  unsigned short* WtW2  = (unsigned short*)p; p += 1310720;   // 5x256x512
  float* pO  = (float*)p;                     p += 16777216;  // 4*8*2048*64 f32
  float* pML = (float*)p;                     p += 524288;
  // total ~89 MB

  // probe dtype (qW ~ N(0, 1/16))
  k_probe<<<1, 256, 0, stream>>>(dflag, (const unsigned short*)qW, 4096);

  // weight transposes (f32-or-bf16 -> bf16 W^T); QKV packed per layer (768 rows)
  // zStride is in ELEMENTS (ushorts)
  k_wt<<<dim3(8, 12, 1), 256, 0, stream>>>(WtD, dinoW, 384, 256, 0, dflag);
  k_wt<<<dim3(8, 8, 5), 256, 0, stream>>>(WtQKV,          qW, 256, 256, 196608, dflag);
  k_wt<<<dim3(8, 8, 5), 256, 0, stream>>>(WtQKV + 65536,  kW, 256, 256, 196608, dflag);
  k_wt<<<dim3(8, 8, 5), 256, 0, stream>>>(WtQKV + 131072, vW, 256, 256, 196608, dflag);
  k_wt<<<dim3(8, 8, 5), 256, 0, stream>>>(WtM, mW, 256, 256, 65536, dflag);
  k_wt<<<dim3(16, 16, 5), 256, 0, stream>>>(WtW1, w1, 512, 512, 262144, dflag);
  k_wt<<<dim3(8, 16, 5), 256, 0, stream>>>(WtW2, w2, 512, 256, 131072, dflag);

  auto attn = [&](int l, float* xF, unsigned short* xB, const unsigned short* srcB,
                  int bs, int L, int S, int split, size_t outOff) {
    const int R = bs * L;
    // layer strides in ELEMENTS: QKV 196608, M 65536, W1 262144, W2 131072
    const unsigned short* Wqkv = WtQKV + (size_t)l * 196608;
    if (xB == srcB) {
      k_gmm<256><<<dim3(12, R / 64), 256, 0, stream>>>(qkvB, 768, 0, xB, 256, xB, 256,
                                                       256, Wqkv, 0);
    } else {
      k_gmm<256><<<dim3(4, R / 64), 256, 0, stream>>>(qkvB, 768, 0, xB, 256, xB, 256,
                                                      256, Wqkv, 0);
      k_gmm<256><<<dim3(8, R / 64), 256, 0, stream>>>(qkvB, 768, 256, srcB, 256, srcB, 256,
                                                      256, Wqkv + 65536, 0);
    }
    const int chunk = S / split;
    k_attn_p<<<dim3(L / 64, bs * 4, split), 256, 0, stream>>>(pO, pML, qkvB, 768, L, S, chunk);
    k_attn_c<<<dim3(L / 64, bs * 4), 256, 0, stream>>>(oB, pO, pML, L, split);
    k_gmm<256><<<dim3(4, R / 64), 256, 0, stream>>>(t1B, 256, 0, oB, 256, oB, 256,
                                                    256, WtM + (size_t)l * 65536, 0);
    k_ln_b<<<R, 64, 0, stream>>>(msgB, t1B);
    k_gmm<512><<<dim3(8, R / 64), 256, 0, stream>>>(hB, 512, 0, xB, 256, msgB, 256,
                                                    256, WtW1 + (size_t)l * 262144, 1);
    k_gmm<512><<<dim3(4, R / 64), 256, 0, stream>>>(t3B, 256, 0, hB, 512, hB, 512,
                                                    512, WtW2 + (size_t)l * 131072, 0);
    if (xF) k_lnadd<<<R, 64, 0, stream>>>(xF, xB, t3B);
    else    k_lnadd_out<<<R, 64, 0, stream>>>(d_out, outOff, xB, t3B, dflag);
  };

  // ---- init ----
  k_load2<<<1024, 256, 0, stream>>>(sF, sB, src_feat, 262144, dflag);
  k_load2<<<1024, 256, 0, stream>>>(tF, tB, tgt_feat, 262144, dflag);
  k_loadb<<<1536, 256, 0, stream>>>(d2B, src2d, 393216, dflag);
  k_gmm<384><<<dim3(4, 64), 256, 0, stream>>>(s2B, 256, 0, d2B, 384, d2B, 384, 384, WtD, 0);
  k_loadb<<<1536, 256, 0, stream>>>(d2B, tgt2d, 393216, dflag);
  k_gmm<384><<<dim3(4, 64), 256, 0, stream>>>(t2B, 256, 0, d2B, 384, d2B, 384, 384, WtD, 0);

  // layer 0: self (+dino)
  k_add_dino<<<1024, 256, 0, stream>>>(sF, sB, s2B, 262144);
  k_add_dino<<<1024, 256, 0, stream>>>(tF, tB, t2B, 262144);
  attn(0, sF, sB, sB, 2, 2048, 2048, 4, 0);
  attn(0, tF, tB, tB, 2, 2048, 2048, 4, 0);
  // layer 1: cross (tgt uses updated src)
  attn(1, sF, sB, tB, 2, 2048, 2048, 4, 0);
  attn(1, tF, tB, sB, 2, 2048, 2048, 4, 0);
  // layer 2: self (+dino)
  k_add_dino<<<1024, 256, 0, stream>>>(sF, sB, s2B, 262144);
  k_add_dino<<<1024, 256, 0, stream>>>(tF, tB, t2B, 262144);
  attn(2, sF, sB, sB, 2, 2048, 2048, 4, 0);
  attn(2, tF, tB, tB, 2, 2048, 2048, 4, 0);
  // layer 3: cross
  attn(3, sF, sB, tB, 2, 2048, 2048, 4, 0);
  attn(3, tF, tB, sB, 2, 2048, 2048, 4, 0);
  // semantic gather (pad index 2048 -> zeros)
  k_gather_b<<<8192, 64, 0, stream>>>(sSubB, sF, s_sub);
  k_gather_b<<<8192, 64, 0, stream>>>(tSubB, tF, t_sub);
  // layer 4: semantic subspace cross — both use ORIGINAL subsets
  attn(4, nullptr, sSubB, tSubB, 16, 512, 512, 2, 2097152);
  attn(4, nullptr, tSubB, sSubB, 16, 512, 512, 2, 4194304);

  // main outputs
  k_store<<<1024, 256, 0, stream>>>(d_out, 0,       sF, 262144, dflag);
  k_store<<<1024, 256, 0, stream>>>(d_out, 1048576, tF, 262144, dflag);
}

// Round 8
// 1330.309 us; speedup vs baseline: 4.3603x; 1.0458x over previous
//
#include <hip/hip_runtime.h>
#include <hip/hip_bf16.h>
#include <cstdint>
#include <cstddef>

// ---------------------------------------------------------------------------
// SemanticTransformer forward. bf16 MFMA compute, f32 residual stream.
// Round 8: batched independent work (self layers M=8192, semantic M=16384),
// single-dispatch cross QKV via row-XOR, 2048-wg attention grids, fewer
// dispatches (~74), buffer aliasing.
// B=2, N=2048, C=256, NHEAD=4, DH=64, D2=384, G=16, Lp=512, layers=5
// ---------------------------------------------------------------------------

typedef __attribute__((ext_vector_type(8))) short bf16x8;   // 8 bf16, 4 VGPRs
typedef __attribute__((ext_vector_type(4))) float f32x4;

__device__ __forceinline__ float b2f(unsigned short u) {
  union { unsigned int i; float f; } v; v.i = ((unsigned int)u) << 16; return v.f;
}
__device__ __forceinline__ unsigned short f2b(float f) {
  __hip_bfloat16 h = __float2bfloat16(f);
  union { __hip_bfloat16 h; unsigned short u; } v; v.h = h; return v.u;
}

// ---------------- dtype probe ----------------------------------------------
__global__ __launch_bounds__(256) void k_probe(int* __restrict__ flag,
                                               const unsigned short* __restrict__ w,
                                               int n) {
  __shared__ int ok[256];
  const int t = threadIdx.x;
  int good = 1;
  for (int i = t; i < n; i += 256) {
    float v = fabsf(b2f(w[i]));
    if (!(v < 1e3f)) good = 0;
  }
  ok[t] = good;
  __syncthreads();
  for (int s = 128; s; s >>= 1) {
    if (t < s) ok[t] &= ok[t + s];
    __syncthreads();
  }
  if (t == 0) *flag = ok[0];   // 1 = bf16 data, 0 = f32 data
}

// ---------------- input loads ----------------------------------------------
__global__ __launch_bounds__(256) void k_load2(float* __restrict__ dF,
                                               unsigned short* __restrict__ dB,
                                               const void* __restrict__ src,
                                               int n4, const int* __restrict__ flag) {
  int i = blockIdx.x * 256 + threadIdx.x;
  if (i >= n4) return;
  float4 f;
  if (*flag) {
    ushort4 u = ((const ushort4*)src)[i];
    f.x = b2f(u.x); f.y = b2f(u.y); f.z = b2f(u.z); f.w = b2f(u.w);
  } else {
    f = ((const float4*)src)[i];
  }
  ((float4*)dF)[i] = f;
  ushort4 o; o.x = f2b(f.x); o.y = f2b(f.y); o.z = f2b(f.z); o.w = f2b(f.w);
  ((ushort4*)dB)[i] = o;
}

__global__ __launch_bounds__(256) void k_loadb(unsigned short* __restrict__ dB,
                                               const void* __restrict__ src,
                                               int n4, const int* __restrict__ flag) {
  int i = blockIdx.x * 256 + threadIdx.x;
  if (i >= n4) return;
  if (*flag) {
    ((ushort4*)dB)[i] = ((const ushort4*)src)[i];
    return;
  }
  float4 f = ((const float4*)src)[i];
  ushort4 o; o.x = f2b(f.x); o.y = f2b(f.y); o.z = f2b(f.z); o.w = f2b(f.w);
  ((ushort4*)dB)[i] = o;
}

__global__ __launch_bounds__(256) void k_store(void* __restrict__ out, size_t off,
                                               const float* __restrict__ src,
                                               int n4, const int* __restrict__ flag) {
  int i = blockIdx.x * 256 + threadIdx.x;
  if (i >= n4) return;
  float4 f = ((const float4*)src)[i];
  if (*flag) {
    ushort4 u; u.x = f2b(f.x); u.y = f2b(f.y); u.z = f2b(f.z); u.w = f2b(f.w);
    ((ushort4*)((unsigned short*)out + off))[i] = u;
  } else {
    ((float4*)((float*)out + off))[i] = f;
  }
}

// dino residual: xF += addB; xB = bf16(xF)
__global__ __launch_bounds__(256) void k_add_dino(float* __restrict__ xF,
                                                  unsigned short* __restrict__ xB,
                                                  const unsigned short* __restrict__ addB,
                                                  int n4) {
  int i = blockIdx.x * 256 + threadIdx.x;
  if (i >= n4) return;
  float4 a = ((const float4*)xF)[i];
  ushort4 u = ((const ushort4*)addB)[i];
  a.x += b2f(u.x); a.y += b2f(u.y); a.z += b2f(u.z); a.w += b2f(u.w);
  ((float4*)xF)[i] = a;
  ushort4 o; o.x = f2b(a.x); o.y = f2b(a.y); o.z = f2b(a.z); o.w = f2b(a.w);
  ((ushort4*)xB)[i] = o;
}

// ---------------- weight transpose+cast: Wt[z][n][k] = W[z][k][n] ----------
__global__ __launch_bounds__(256) void k_wt(unsigned short* __restrict__ Wt,
                                            const void* __restrict__ W,
                                            int K, int N, int zStride,
                                            const int* __restrict__ flag) {
  __shared__ float tile[32][33];
  const int isbf = *flag;
  const int z = blockIdx.z;
  const unsigned short* Wb = (const unsigned short*)W + (size_t)z * K * N;
  const float* Wf = (const float*)W + (size_t)z * K * N;
  unsigned short* Wo = Wt + (size_t)z * zStride;
  const int nx = blockIdx.x * 32, ky = blockIdx.y * 32;
  const int tx = threadIdx.x & 31, ty = threadIdx.x >> 5;  // ty 0..7
#pragma unroll
  for (int i = 0; i < 4; ++i) {
    int k = ky + ty + i * 8;
    float v = isbf ? b2f(Wb[(size_t)k * N + nx + tx]) : Wf[(size_t)k * N + nx + tx];
    tile[ty + i * 8][tx] = v;
  }
  __syncthreads();
#pragma unroll
  for (int i = 0; i < 4; ++i) {
    int nn = ty + i * 8;
    Wo[(size_t)(nx + nn) * K + ky + tx] = f2b(tile[tx][nn]);
  }
}

// ---------------- MFMA GEMM, compile-time K --------------------------------
// Y[arow-relative output rows][n] = relu?( A[arow] @ Wt ).
// arow = rowOff + row; for output columns n0 >= xorColStart, arow ^= rowXor
// (lets one dispatch compute Q from x-rows and K/V from source-rows).
// A concat on K: k<K1 from A1 else A2 (for W1 [x; msg]).
template<int KTOT>
__global__ __launch_bounds__(256, 4) void k_gmm(unsigned short* __restrict__ Y, int ldy,
                                                const unsigned short* __restrict__ A1, int lda1,
                                                const unsigned short* __restrict__ A2, int lda2,
                                                int K1,
                                                const unsigned short* __restrict__ Wt,
                                                int relu, int rowOff, int rowXor,
                                                int xorColStart) {
  const int tid = threadIdx.x;
  const int wq = tid >> 6, lane = tid & 63;
  const int l16 = lane & 15, quad = lane >> 4;
  const int n0 = blockIdx.x * 64, m0 = blockIdx.y * 64;
  const int row = m0 + wq * 16 + l16;
  int arow = rowOff + row;
  if (n0 >= xorColStart) arow ^= rowXor;

  f32x4 acc[4];
#pragma unroll
  for (int i = 0; i < 4; ++i) acc[i] = (f32x4){0.f, 0.f, 0.f, 0.f};

#pragma unroll
  for (int k0 = 0; k0 < KTOT; k0 += 32) {
    const unsigned short* ap = (k0 < K1)
        ? (A1 + (size_t)arow * lda1 + k0)
        : (A2 + (size_t)arow * lda2 + (k0 - K1));
    bf16x8 a = *(const bf16x8*)(ap + quad * 8);
#pragma unroll
    for (int nb = 0; nb < 4; ++nb) {
      bf16x8 b = *(const bf16x8*)(Wt + (size_t)(n0 + nb * 16 + l16) * KTOT + k0 + quad * 8);
      acc[nb] = __builtin_amdgcn_mfma_f32_16x16x32_bf16(a, b, acc[nb], 0, 0, 0);
    }
  }

#pragma unroll
  for (int r = 0; r < 4; ++r) {
    unsigned short* yp = Y + (size_t)(m0 + wq * 16 + quad * 4 + r) * ldy + n0;
#pragma unroll
    for (int nb = 0; nb < 4; ++nb) {
      float v = acc[nb][r];
      if (relu) v = fmaxf(v, 0.f);
      yp[nb * 16 + l16] = f2b(v);
    }
  }
}

// ---------------- split-S MFMA flash attention: partial (transposed) -------
// QKV: rows = n*L|S + idx, cols: q at 0, k at 256, v at 512 (lda=768), head h
// at +h*64. Grid: (L/64, NHt, split), n = nh>>2. 4 waves x 16 queries.
// Scores TRANSPOSED (S^T = K Q^T): softmax in-register + 2 cross-quad
// shuffles; O^T = V^T P; epilogue transposes via LDS.
__global__ __launch_bounds__(256, 4) void k_attn_p(float* __restrict__ pO,
                                                   float* __restrict__ pML,
                                                   const unsigned short* __restrict__ QKV,
                                                   int lda, int L, int S, int chunk) {
  __shared__ __align__(16) unsigned short Vt[2][64][72];   // V^T: [buf][dh][key]
  __shared__ __align__(16) unsigned short Ps[4][16][72];   // per-wave P: [q][key]
  const int tid = threadIdx.x;
  const int wq = tid >> 6, lane = tid & 63;
  const int l16 = lane & 15, quad = lane >> 4;
  const int q0 = blockIdx.x * 64;
  const int nh = blockIdx.y, NHt = gridDim.y;
  const int n = nh >> 2, h = nh & 3;
  const int s0 = blockIdx.z * chunk;

  const unsigned short* Kb = QKV + 256;
  const unsigned short* Vb = QKV + 512;

  const unsigned short* qp = QKV + (size_t)(n * L + q0 + wq * 16 + l16) * lda + h * 64;
  bf16x8 qa0 = *(const bf16x8*)(qp + quad * 8);
  bf16x8 qa1 = *(const bf16x8*)(qp + 32 + quad * 8);

  f32x4 acc[4];   // O^T: acc[db][r] = O^T[db*16+quad*4+r][q=l16]
#pragma unroll
  for (int i = 0; i < 4; ++i) acc[i] = (f32x4){0.f, 0.f, 0.f, 0.f};
  float m_ = -1e30f, l_ = 0.f;   // per-lane (query l16), replicated across quads

  const int sdh0 = wq * 16;   // V staging: wave wq covers dh rows [wq*16, +16)
  const int skey = lane;      // lane = key

  bf16x8 kf[8];
  uint4 va, vbr;
  {
    const unsigned short* vp = Vb + (size_t)(n * S + s0 + skey) * lda + h * 64 + sdh0;
    va = *(const uint4*)vp; vbr = *(const uint4*)(vp + 8);
  }
#pragma unroll
  for (int kb = 0; kb < 4; ++kb) {
    const unsigned short* kp = Kb + (size_t)(n * S + s0 + kb * 16 + l16) * lda + h * 64;
    kf[2 * kb]     = *(const bf16x8*)(kp + quad * 8);
    kf[2 * kb + 1] = *(const bf16x8*)(kp + 32 + quad * 8);
  }
  {
    const unsigned short* p0 = (const unsigned short*)&va;
    const unsigned short* p1 = (const unsigned short*)&vbr;
#pragma unroll
    for (int i = 0; i < 8; ++i) Vt[0][sdh0 + i][skey] = p0[i];
#pragma unroll
    for (int i = 0; i < 8; ++i) Vt[0][sdh0 + 8 + i][skey] = p1[i];
  }
  if (chunk > 64) {
    const unsigned short* vp = Vb + (size_t)(n * S + s0 + 64 + skey) * lda + h * 64 + sdh0;
    va = *(const uint4*)vp; vbr = *(const uint4*)(vp + 8);
  }
  __syncthreads();

  int cur = 0;
  for (int t = 0; t < chunk; t += 64) {
    // S^T tile = K Q^T
    f32x4 sc[4];
#pragma unroll
    for (int kb = 0; kb < 4; ++kb) {
      f32x4 z = (f32x4){0.f, 0.f, 0.f, 0.f};
      z = __builtin_amdgcn_mfma_f32_16x16x32_bf16(kf[2 * kb], qa0, z, 0, 0, 0);
      z = __builtin_amdgcn_mfma_f32_16x16x32_bf16(kf[2 * kb + 1], qa1, z, 0, 0, 0);
      sc[kb] = z;
    }
    // prefetch K(t+64)
    {
      int tn = t + 64; if (tn >= chunk) tn = t;
#pragma unroll
      for (int kb = 0; kb < 4; ++kb) {
        const unsigned short* kp = Kb + (size_t)(n * S + s0 + tn + kb * 16 + l16) * lda + h * 64;
        kf[2 * kb]     = *(const bf16x8*)(kp + quad * 8);
        kf[2 * kb + 1] = *(const bf16x8*)(kp + 32 + quad * 8);
      }
    }
    // online softmax: in-register tree + 2 cross-quad shuffles
    f32x4 mv01, mv;
#pragma unroll
    for (int r = 0; r < 4; ++r) mv01[r] = fmaxf(sc[0][r], sc[1][r]);
#pragma unroll
    for (int r = 0; r < 4; ++r) mv[r] = fmaxf(mv01[r], fmaxf(sc[2][r], sc[3][r]));
    float mx = fmaxf(fmaxf(mv[0], mv[1]), fmaxf(mv[2], mv[3])) * 0.125f;
    mx = fmaxf(mx, __shfl_xor(mx, 16));
    mx = fmaxf(mx, __shfl_xor(mx, 32));
    float mn = fmaxf(m_, mx);
    float alpha = __expf(m_ - mn);
    m_ = mn;
    float rs = 0.f;
#pragma unroll
    for (int kb = 0; kb < 4; ++kb)
#pragma unroll
      for (int r = 0; r < 4; ++r) {
        float pv = __expf(sc[kb][r] * 0.125f - mn);
        sc[kb][r] = pv;
        rs += pv;
      }
    rs += __shfl_xor(rs, 16);
    rs += __shfl_xor(rs, 32);
    l_ = l_ * alpha + rs;
#pragma unroll
    for (int nb = 0; nb < 4; ++nb)
#pragma unroll
      for (int r = 0; r < 4; ++r) acc[nb][r] *= alpha;

    // stage V^T(t+64) into the other buffer
    if (t + 64 < chunk) {
      const unsigned short* p0 = (const unsigned short*)&va;
      const unsigned short* p1 = (const unsigned short*)&vbr;
#pragma unroll
      for (int i = 0; i < 8; ++i) Vt[cur ^ 1][sdh0 + i][skey] = p0[i];
#pragma unroll
      for (int i = 0; i < 8; ++i) Vt[cur ^ 1][sdh0 + 8 + i][skey] = p1[i];
    }
    // prefetch V(t+128)
    if (t + 128 < chunk) {
      const unsigned short* vp = Vb + (size_t)(n * S + s0 + t + 128 + skey) * lda + h * 64 + sdh0;
      va = *(const uint4*)vp; vbr = *(const uint4*)(vp + 8);
    }

    // P^T -> LDS as P[q][key]; packed b64 stores
#pragma unroll
    for (int kb = 0; kb < 4; ++kb) {
      ushort4 u;
      u.x = f2b(sc[kb][0]); u.y = f2b(sc[kb][1]);
      u.z = f2b(sc[kb][2]); u.w = f2b(sc[kb][3]);
      *(ushort4*)&Ps[wq][l16][kb * 16 + quad * 4] = u;
    }

    // O^T += V^T P
    bf16x8 ps0 = *(const bf16x8*)&Ps[wq][l16][quad * 8];
    bf16x8 ps1 = *(const bf16x8*)&Ps[wq][l16][32 + quad * 8];
#pragma unroll
    for (int db = 0; db < 4; ++db) {
      bf16x8 vb0 = *(const bf16x8*)&Vt[cur][db * 16 + l16][quad * 8];
      bf16x8 vb1 = *(const bf16x8*)&Vt[cur][db * 16 + l16][32 + quad * 8];
      acc[db] = __builtin_amdgcn_mfma_f32_16x16x32_bf16(vb0, ps0, acc[db], 0, 0, 0);
      acc[db] = __builtin_amdgcn_mfma_f32_16x16x32_bf16(vb1, ps1, acc[db], 0, 0, 0);
    }
    __syncthreads();
    cur ^= 1;
  }

  // epilogue: transpose O^T -> O via LDS (reuse Vt as f32 [64][68])
  float* Ot = (float*)&Vt[0][0][0];
#pragma unroll
  for (int db = 0; db < 4; ++db)
    *(f32x4*)&Ot[(size_t)(wq * 16 + l16) * 68 + db * 16 + quad * 4] = acc[db];
  __syncthreads();
#pragma unroll
  for (int i = 0; i < 16; ++i) {
    const int row = q0 + wq * 16 + i;
    pO[((size_t)(blockIdx.z * NHt + nh) * L + row) * 64 + lane] =
        Ot[(size_t)(wq * 16 + i) * 68 + lane];
  }
  if (quad == 0) {
    float* pml = pML + ((size_t)(blockIdx.z * NHt + nh) * L + q0 + wq * 16 + l16) * 2;
    pml[0] = m_; pml[1] = l_;
  }
}

// combine: 256 threads = 64 queries x 4 dim-quarters; O bf16 (row stride 256)
__global__ __launch_bounds__(256) void k_attn_c(unsigned short* __restrict__ O,
                                                const float* __restrict__ pO,
                                                const float* __restrict__ pML,
                                                int L, int split) {
  const int tid = threadIdx.x;
  const int q = blockIdx.x * 64 + (tid >> 2);
  const int part = tid & 3;
  const int nh = blockIdx.y, NHt = gridDim.y;
  const int n = nh >> 2, h = nh & 3;

  float M = -1e30f;
  for (int sp = 0; sp < split; ++sp)
    M = fmaxf(M, pML[(((size_t)sp * NHt + nh) * L + q) * 2]);

  float4 acc[4];
#pragma unroll
  for (int i = 0; i < 4; ++i) { acc[i].x = 0.f; acc[i].y = 0.f; acc[i].z = 0.f; acc[i].w = 0.f; }
  float lsum = 0.f;
  for (int sp = 0; sp < split; ++sp) {
    const float* pml = pML + (((size_t)sp * NHt + nh) * L + q) * 2;
    float e = __expf(pml[0] - M);
    lsum = fmaf(pml[1], e, lsum);
    const float4* po = (const float4*)(pO + (((size_t)sp * NHt + nh) * L + q) * 64 + part * 16);
#pragma unroll
    for (int i = 0; i < 4; ++i) {
      float4 v = po[i];
      acc[i].x = fmaf(v.x, e, acc[i].x);
      acc[i].y = fmaf(v.y, e, acc[i].y);
      acc[i].z = fmaf(v.z, e, acc[i].z);
      acc[i].w = fmaf(v.w, e, acc[i].w);
    }
  }
  float inv = 1.0f / lsum;
  unsigned short* op = O + ((size_t)(n * L + q)) * 256 + h * 64 + part * 16;
#pragma unroll
  for (int i = 0; i < 4; ++i) {
    ushort4 u;
    u.x = f2b(acc[i].x * inv); u.y = f2b(acc[i].y * inv);
    u.z = f2b(acc[i].z * inv); u.w = f2b(acc[i].w * inv);
    ((ushort4*)op)[i] = u;
  }
}

// ---------------- LayerNorm over 256 (no affine) ----------------------------
__device__ __forceinline__ void row_stats(float4 v, float& mean, float& inv) {
  float s  = v.x + v.y + v.z + v.w;
  float s2 = fmaf(v.x, v.x, fmaf(v.y, v.y, fmaf(v.z, v.z, v.w * v.w)));
#pragma unroll
  for (int off = 32; off >= 1; off >>= 1) {
    s  += __shfl_xor(s,  off, 64);
    s2 += __shfl_xor(s2, off, 64);
  }
  mean = s * (1.f / 256.f);
  float var = s2 * (1.f / 256.f) - mean * mean;
  inv = rsqrtf(var + 1e-5f);
}

__device__ __forceinline__ float4 ld_bf4(const unsigned short* p, size_t i) {
  ushort4 u = ((const ushort4*)p)[i];
  float4 f; f.x = b2f(u.x); f.y = b2f(u.y); f.z = b2f(u.z); f.w = b2f(u.w);
  return f;
}

__global__ __launch_bounds__(64) void k_ln_b(unsigned short* __restrict__ dst,
                                             const unsigned short* __restrict__ src) {
  const size_t row = blockIdx.x;
  const int t = threadIdx.x;
  float4 v = ld_bf4(src + row * 256, t);
  float mean, inv; row_stats(v, mean, inv);
  ushort4 u;
  u.x = f2b((v.x - mean) * inv); u.y = f2b((v.y - mean) * inv);
  u.z = f2b((v.z - mean) * inv); u.w = f2b((v.w - mean) * inv);
  ((ushort4*)(dst + row * 256))[t] = u;
}

__global__ __launch_bounds__(64) void k_lnadd(float* __restrict__ xF,
                                              unsigned short* __restrict__ xB,
                                              const unsigned short* __restrict__ t3) {
  const size_t row = blockIdx.x;
  const int t = threadIdx.x;
  float4 v = ld_bf4(t3 + row * 256, t);
  float mean, inv; row_stats(v, mean, inv);
  float4 xv = ((const float4*)(xF + row * 256))[t];
  float4 r;
  r.x = xv.x + (v.x - mean) * inv; r.y = xv.y + (v.y - mean) * inv;
  r.z = xv.z + (v.z - mean) * inv; r.w = xv.w + (v.w - mean) * inv;
  ((float4*)(xF + row * 256))[t] = r;
  ushort4 u; u.x = f2b(r.x); u.y = f2b(r.y); u.z = f2b(r.z); u.w = f2b(r.w);
  ((ushort4*)(xB + row * 256))[t] = u;
}

__global__ __launch_bounds__(64) void k_lnadd_out(void* __restrict__ out, size_t off,
                                                  const unsigned short* __restrict__ xB,
                                                  const unsigned short* __restrict__ t3,
                                                  const int* __restrict__ flag) {
  const size_t row = blockIdx.x;
  const int t = threadIdx.x;
  float4 v = ld_bf4(t3 + row * 256, t);
  float mean, inv; row_stats(v, mean, inv);
  float4 xv = ld_bf4(xB + row * 256, t);
  float4 r;
  r.x = xv.x + (v.x - mean) * inv; r.y = xv.y + (v.y - mean) * inv;
  r.z = xv.z + (v.z - mean) * inv; r.w = xv.w + (v.w - mean) * inv;
  if (*flag) {
    ushort4 u; u.x = f2b(r.x); u.y = f2b(r.y); u.z = f2b(r.z); u.w = f2b(r.w);
    ((ushort4*)((unsigned short*)out + off + row * 256))[t] = u;
  } else {
    ((float4*)((float*)out + off + row * 256))[t] = r;
  }
}

// ---------------- semantic gather, batched (index 2048 -> zeros) ------------
// row 0..16383: rows <8192 gather from src half (sF) with sIdx, else tgt half.
__global__ __launch_bounds__(64) void k_gather2(unsigned short* __restrict__ dst,
                                                const float* __restrict__ sF,
                                                const int* __restrict__ sIdx,
                                                const int* __restrict__ tIdx) {
  const int row = blockIdx.x;
  const int half = row >> 13;
  const int r = row & 8191;
  const int g = r >> 9;
  const int b = g >> 3;               // mask_num = 8
  const int id = half ? tIdx[r] : sIdx[r];
  float4 v = {0.f, 0.f, 0.f, 0.f};
  if ((unsigned)id < 2048u) {
    const float* base = sF + (size_t)(half * 2 + b) * 524288;   // 2048*256
    v = ((const float4*)(base + (size_t)id * 256))[threadIdx.x];
  }
  ushort4 u; u.x = f2b(v.x); u.y = f2b(v.y); u.z = f2b(v.z); u.w = f2b(v.w);
  ((ushort4*)(dst + (size_t)row * 256))[threadIdx.x] = u;
}

// ---------------------------------------------------------------------------
extern "C" void kernel_launch(void* const* d_in, const int* in_sizes, int n_in,
                              void* d_out, int out_size, void* d_ws, size_t ws_size,
                              hipStream_t stream) {
  const void* src_feat = d_in[0];
  const void* tgt_feat = d_in[1];
  const int* s_sub = (const int*)d_in[6];
  const int* t_sub = (const int*)d_in[7];
  const void* src2d = d_in[11];
  const void* tgt2d = d_in[12];
  const void* dinoW = d_in[14];
  const void* qW = d_in[15];
  const void* kW = d_in[16];
  const void* vW = d_in[17];
  const void* mW = d_in[18];
  const void* w1 = d_in[19];
  const void* w2 = d_in[20];

  const int BIG = 1 << 30;
  char* p = (char*)d_ws;
  int* dflag = (int*)p;                       p += 256;
  float* sF = (float*)p;                      p += 4194304;   // [sF|tF] adjacent
  float* tF = (float*)p;                      p += 4194304;
  unsigned short* sB    = (unsigned short*)p; p += 2097152;   // [sB|tB] adjacent
  unsigned short* tB    = (unsigned short*)p; p += 2097152;
  unsigned short* s2B   = (unsigned short*)p; p += 2097152;   // [s2B|t2B] adjacent
  unsigned short* t2B   = (unsigned short*)p; p += 2097152;
  unsigned short* d2B   = (unsigned short*)p; p += 3145728;   // 4096x384 (reused)
  unsigned short* sSubB = (unsigned short*)p; p += 4194304;   // [sSub|tSub] adjacent
  unsigned short* tSubB = (unsigned short*)p; p += 4194304;
  // region A (25.2MB): qkvB (16384x768) overlaid by t1B / msgB / oB after attn_p
  unsigned short* qkvB  = (unsigned short*)p;
  unsigned short* t1B   = (unsigned short*)p;                 // A + 0      (8.4MB)
  unsigned short* msgB  = (unsigned short*)(p + 8388608);     // A + 8.4MB  (8.4MB)
  unsigned short* oB    = (unsigned short*)(p + 16777216);    // A + 16.8MB (8.4MB)
  p += 25165824;
  // region B (25.2MB): hB (16384x512) + t3B (16384x256)
  unsigned short* hB    = (unsigned short*)p;
  unsigned short* t3B   = (unsigned short*)(p + 16777216);
  p += 25165824;
  unsigned short* WtD   = (unsigned short*)p; p += 196608;    // 256x384
  unsigned short* WtQKV = (unsigned short*)p; p += 1966080;   // 5x768x256
  unsigned short* WtM   = (unsigned short*)p; p += 655360;    // 5x256x256
  unsigned short* WtW1  = (unsigned short*)p; p += 2621440;   // 5x512x512
  unsigned short* WtW2  = (unsigned short*)p; p += 1310720;   // 5x256x512
  float* pO  = (float*)p;                     p += 33554432;  // split*NHt*L*64 f32
  float* pML = (float*)p;                     p += 2097152;
  // total ~121 MB

  // probe dtype (qW ~ N(0, 1/16))
  k_probe<<<1, 256, 0, stream>>>(dflag, (const unsigned short*)qW, 4096);

  // weight transposes; QKV packed per layer (768 rows). zStride in ELEMENTS.
  k_wt<<<dim3(8, 12, 1), 256, 0, stream>>>(WtD, dinoW, 384, 256, 0, dflag);
  k_wt<<<dim3(8, 8, 5), 256, 0, stream>>>(WtQKV,          qW, 256, 256, 196608, dflag);
  k_wt<<<dim3(8, 8, 5), 256, 0, stream>>>(WtQKV + 65536,  kW, 256, 256, 196608, dflag);
  k_wt<<<dim3(8, 8, 5), 256, 0, stream>>>(WtQKV + 131072, vW, 256, 256, 196608, dflag);
  k_wt<<<dim3(8, 8, 5), 256, 0, stream>>>(WtM, mW, 256, 256, 65536, dflag);
  k_wt<<<dim3(16, 16, 5), 256, 0, stream>>>(WtW1, w1, 512, 512, 262144, dflag);
  k_wt<<<dim3(8, 16, 5), 256, 0, stream>>>(WtW2, w2, 512, 256, 131072, dflag);

  // One attention block: QKV (single dispatch, row-XOR for KV), partial,
  // combine, M-proj, LN, FFN, residual.
  auto attnB = [&](int l, const unsigned short* Abase, int rowOff, int rowXor,
                   int M, int L, int S, int split, int NHt,
                   float* xF, unsigned short* xB, size_t outOff) {
    k_gmm<256><<<dim3(12, M / 64), 256, 0, stream>>>(
        qkvB, 768, Abase, 256, Abase, 256, 256,
        WtQKV + (size_t)l * 196608, 0, rowOff, rowXor, 256);
    const int chunk = S / split;
    k_attn_p<<<dim3(L / 64, NHt, split), 256, 0, stream>>>(pO, pML, qkvB, 768, L, S, chunk);
    k_attn_c<<<dim3(L / 64, NHt), 256, 0, stream>>>(oB, pO, pML, L, split);
    k_gmm<256><<<dim3(4, M / 64), 256, 0, stream>>>(
        t1B, 256, oB, 256, oB, 256, 256, WtM + (size_t)l * 65536, 0, 0, 0, BIG);
    k_ln_b<<<M, 64, 0, stream>>>(msgB, t1B);
    k_gmm<512><<<dim3(8, M / 64), 256, 0, stream>>>(
        hB, 512, xB, 256, msgB, 256, 256, WtW1 + (size_t)l * 262144, 1, 0, 0, BIG);
    k_gmm<512><<<dim3(4, M / 64), 256, 0, stream>>>(
        t3B, 256, hB, 512, hB, 512, 512, WtW2 + (size_t)l * 131072, 0, 0, 0, BIG);
    if (xF) k_lnadd<<<M, 64, 0, stream>>>(xF, xB, t3B);
    else    k_lnadd_out<<<M, 64, 0, stream>>>(d_out, outOff, xB, t3B, dflag);
  };

  // ---- init ----
  k_load2<<<1024, 256, 0, stream>>>(sF, sB, src_feat, 262144, dflag);
  k_load2<<<1024, 256, 0, stream>>>(tF, tB, tgt_feat, 262144, dflag);
  k_loadb<<<1536, 256, 0, stream>>>(d2B, src2d, 393216, dflag);
  k_gmm<384><<<dim3(4, 64), 256, 0, stream>>>(s2B, 256, d2B, 384, d2B, 384, 384,
                                              WtD, 0, 0, 0, BIG);
  k_loadb<<<1536, 256, 0, stream>>>(d2B, tgt2d, 393216, dflag);
  k_gmm<384><<<dim3(4, 64), 256, 0, stream>>>(t2B, 256, d2B, 384, d2B, 384, 384,
                                              WtD, 0, 0, 0, BIG);

  // layer 0: self, src+tgt batched (M=8192, NHt=16)
  k_add_dino<<<2048, 256, 0, stream>>>(sF, sB, s2B, 524288);
  attnB(0, sB, 0, 0, 8192, 2048, 2048, 4, 16, sF, sB, 0);
  // layer 1: cross (sequential): Q rows from x, KV rows = x^4096
  attnB(1, sB, 0,    4096, 4096, 2048, 2048, 8, 8, sF, sB, 0);
  attnB(1, sB, 4096, 4096, 4096, 2048, 2048, 8, 8, tF, tB, 0);
  // layer 2: self batched (+dino)
  k_add_dino<<<2048, 256, 0, stream>>>(sF, sB, s2B, 524288);
  attnB(2, sB, 0, 0, 8192, 2048, 2048, 4, 16, sF, sB, 0);
  // layer 3: cross
  attnB(3, sB, 0,    4096, 4096, 2048, 2048, 8, 8, sF, sB, 0);
  attnB(3, sB, 4096, 4096, 4096, 2048, 2048, 8, 8, tF, tB, 0);
  // semantic gather (batched, pad index 2048 -> zeros)
  k_gather2<<<16384, 64, 0, stream>>>(sSubB, sF, s_sub, t_sub);
  // layer 4: semantic subspace cross, both directions batched (M=16384,
  // NHt=128, KV rows = rows ^ 8192 -> opposite subset)
  attnB(4, sSubB, 0, 8192, 16384, 512, 512, 2, 128, nullptr, sSubB, 2097152);

  // main outputs (sF|tF contiguous -> out[0..2097152))
  k_store<<<2048, 256, 0, stream>>>(d_out, 0, sF, 524288, dflag);
}